// Round 13
// baseline (1104.062 us; speedup 1.0000x reference)
//
#include <hip/hip_runtime.h>
#include <hip/hip_bf16.h>
#include <cstddef>

// ---------------- constants ----------------
#define NB 8
#define HIDC 256
#define NHEAD 8
#define HDIM 32
#define TTOK 33320
#define STOT 4165
#define VTP 33440
#define QKVS 768          // merged qkv row stride
// 1/sqrt(32) * log2(e): fold softmax scale AND exp->exp2 conversion into Wq/bq
#define QSC2 0.2550348757f
#define BN1_CH 128        // bn1 chunks per scale (512 blocks total)

static const int H_SZ[4]   = {56, 28, 14, 7};
static const int S_SZ[4]   = {3136, 784, 196, 49};
static const int D_IN[4]   = {64, 128, 256, 512};
static const int BOFF[4]   = {0, 25088, 31360, 32928};
static const int SKPAD_H[4]= {3136, 784, 200, 56};
static const int VWOFF_H[4]= {0, 25088, 31360, 32960};

__constant__ int DC_S[4]     = {3136, 784, 196, 49};
__constant__ int DC_HW[4]    = {56, 28, 14, 7};
__constant__ int DC_BOFF[4]  = {0, 25088, 31360, 32928};
__constant__ int DC_GOFF[4]  = {0, 3136, 3920, 4116};
__constant__ int DC_FOS[4]   = {0, 49, 62, 66};   // final_out 64-token block starts (total 67)

// flash pair tables, sorted by Sk desc (long waves dispatch first).
// Pairs 0-2 (Sk=3136): K-SPLIT blocks = 64 q rows, 4 waves x 784-key chunks, LDS combine;
//   nblk = ceil(Sq/64).
// Pairs 3-11: block = 4 independent waves x 64 q rows; nblk = ceil(Sq/256).
__constant__ int FP_SQ[12]   = {784,196,49,3136,196,49,3136,784,49,3136,784,196};
__constant__ int FP_SK[12]   = {3136,3136,3136,784,784,784,196,196,196,49,49,49};
__constant__ int FP_QOFF[12] = {25088,31360,32928,0,31360,32928,0,25088,32928,0,25088,31360};
__constant__ int FP_KOFF[12] = {0,0,0,25088,25088,25088,31360,31360,31360,32928,32928,32928};
__constant__ int FP_VOFF[12] = {0,0,0,25088,25088,25088,31360,31360,31360,32960,32960,32960};
__constant__ int FP_SKP[12]  = {3136,3136,3136,784,784,784,200,200,200,56,56,56};
__constant__ int FP_R[12]    = {0,0,0,0,1,1,1,1,2,2,2,2};
__constant__ int FP_SB0[13]  = {0,13,17,18,31,32,33,46,50,51,64,68,69};

typedef short bf16s;
typedef bf16s bf16x8 __attribute__((ext_vector_type(8)));
typedef float f32x4 __attribute__((ext_vector_type(4)));

// fast f32->bf16 (round half up; |err| == RNE ulp bound, no NaN/inf in data)
static __device__ inline bf16s f2b(float f) {
    return (bf16s)((__float_as_uint(f) + 0x8000u) >> 16);
}
static __device__ inline float b2f(bf16s s) {
    return __uint_as_float(((unsigned)(unsigned short)s) << 16);
}
// pack two f32 -> two bf16 in one dword (single HW instr, RNE; a in low half)
static __device__ inline unsigned cvtpk(float a, float b) {
    unsigned r;
    asm("v_cvt_pk_bf16_f32 %0, %1, %2" : "=v"(r) : "v"(a), "v"(b));
    return r;
}
static __device__ inline float ex2(float x) {
#if __has_builtin(__builtin_amdgcn_exp2f)
    return __builtin_amdgcn_exp2f(x);
#else
    return exp2f(x);
#endif
}
#define MFMA16(a, b, c) __builtin_amdgcn_mfma_f32_16x16x32_bf16(a, b, c, 0, 0, 0)
#define ZERO4 ((f32x4){0.f, 0.f, 0.f, 0.f})

// ---------------- fused weight conversion + W swizzle ----------------
// Swizzled weight layout for gemm3: for (n,k) with n-block c64=n>>6, k-block k32=k>>5:
//   dst = ((c64*(K/32) + k32)*4 + nt)*512 + l15*32 + q*8 + j
// where nt=(n>>4)&3, l15=n&15, q=(k>>3)&3, j=k&7.  One wave W-frag load = 1KB contiguous.
struct CvtArgs {
    const float* src[15];
    void* dst[15];
    int n[15];
    int mode[15];   // 0: bf16 swizzled  1: bf16 swizzled *QSC2  2: f32 copy  3: f32*QSC2
    int K[15];      // weight K (pow2) for swizzle modes
};
__global__ __launch_bounds__(256) void cvt_all(CvtArgs a, int total) {
    int idx = blockIdx.x * 256 + threadIdx.x;
    if (idx >= total) return;
    int seg = 0, off = idx;
    while (off >= a.n[seg]) { off -= a.n[seg]; seg++; }
    float v = a.src[seg][off];
    int m = a.mode[seg];
    if (m == 1 || m == 3) v *= QSC2;
    if (m <= 1) {
        int K = a.K[seg];
        int kz = __builtin_ctz(K);
        int n = off >> kz, k = off & (K - 1);
        int c64 = n >> 6, nt = (n >> 4) & 3, l15 = n & 15;
        int k32 = k >> 5, q = (k >> 3) & 3, j = k & 7;
        int dst = (((c64 * (K >> 5) + k32) * 4 + nt) << 9) + l15 * 32 + q * 8 + j;
        ((bf16s*)a.dst[seg])[dst] = f2b(v);
    } else {
        ((float*)a.dst[seg])[off] = v;
    }
}

// ---------------- tiled transpose f [B,D,S] f32 -> A [B*S, D] bf16 ----------------
__global__ __launch_bounds__(256) void transpose_f2(const float* __restrict__ f,
                                                    bf16s* __restrict__ A, int D, int S) {
    __shared__ float t[32][33];
    int s0 = blockIdx.x * 32, d0 = blockIdx.y * 32, b = blockIdx.z;
    int sl = threadIdx.x & 31, dl = threadIdx.x >> 5;
    #pragma unroll
    for (int dd = 0; dd < 32; dd += 8) {
        int s = s0 + sl;
        t[dl + dd][sl] = (s < S) ? f[((size_t)(b * D + d0 + dl + dd)) * S + s] : 0.f;
    }
    __syncthreads();
    int dc = threadIdx.x & 31, sg = threadIdx.x >> 5;
    #pragma unroll
    for (int ss = 0; ss < 32; ss += 8) {
        int s = s0 + sg + ss;
        if (s < S) A[((size_t)(b * S + s)) * D + d0 + dc] = f2b(t[dc][sg + ss]);
    }
}

// ---------------- MFMA GEMM v4: 64x128 block tile ----------------
// block 256 = 4 waves (2 row-groups x 2 col-groups); wave tile 32x64; block tile 64x128.
// EPI 0: bf16->Cb | 1: f32->Cf + bf16->Cb | 4: f32->Cf
template <int EPI>
__global__ __launch_bounds__(256) void gemm3(
    const bf16s* __restrict__ A, const bf16s* __restrict__ A2,
    const bf16s* __restrict__ W, const float* __restrict__ bias,
    float* __restrict__ Cf, bf16s* __restrict__ Cb, const bf16s* __restrict__ Gaux,
    int M, int N, int K, int K1)
{
    int tid = threadIdx.x, lane = tid & 63, wave = tid >> 6;
    int l15 = lane & 15, quad = lane >> 4;
    int row0 = blockIdx.y * 64 + (wave >> 1) * 32;
    int col0 = blockIdx.x * 128 + (wave & 1) * 64;
    int K2 = K - K1;
    int nk = K >> 5;
    int c64 = (blockIdx.x << 1) + (wave & 1);
    const bf16s* wbase = W + (size_t)c64 * ((size_t)nk << 11) + l15 * 32 + quad * 8;
    int ra[2];
    #pragma unroll
    for (int mt = 0; mt < 2; mt++) ra[mt] = min(row0 + mt * 16 + l15, M - 1);

    f32x4 acc[2][4];
    #pragma unroll
    for (int i = 0; i < 2; i++)
        #pragma unroll
        for (int j = 0; j < 4; j++) acc[i][j] = ZERO4;

    bf16x8 aA[2], wA[4], aB[2], wB[4];

    auto loadA = [&](bf16x8* af, int k32) {
        int kk = (k32 << 5) + quad * 8;
        if (kk < K1) {
            #pragma unroll
            for (int mt = 0; mt < 2; mt++)
                af[mt] = *(const bf16x8*)(A + (size_t)ra[mt] * K1 + kk);
        } else {
            int k2 = kk - K1;
            #pragma unroll
            for (int mt = 0; mt < 2; mt++)
                af[mt] = *(const bf16x8*)(A2 + (size_t)ra[mt] * K2 + k2);
        }
    };
    auto loadW = [&](bf16x8* wf, int k32) {
        const bf16s* p = wbase + ((size_t)k32 << 11);
        #pragma unroll
        for (int nt = 0; nt < 4; nt++)
            wf[nt] = *(const bf16x8*)(p + nt * 512);
    };

    loadA(aA, 0); loadW(wA, 0);
    for (int k32 = 0; k32 < nk; k32 += 2) {
        loadA(aB, k32 + 1); loadW(wB, k32 + 1);
        #pragma unroll
        for (int mt = 0; mt < 2; mt++)
            #pragma unroll
            for (int nt = 0; nt < 4; nt++)
                acc[mt][nt] = MFMA16(aA[mt], wA[nt], acc[mt][nt]);
        if (k32 + 2 < nk) { loadA(aA, k32 + 2); loadW(wA, k32 + 2); }
        #pragma unroll
        for (int mt = 0; mt < 2; mt++)
            #pragma unroll
            for (int nt = 0; nt < 4; nt++)
                acc[mt][nt] = MFMA16(aB[mt], wB[nt], acc[mt][nt]);
    }

    #pragma unroll
    for (int mt = 0; mt < 2; mt++) {
        int rowb = row0 + mt * 16 + quad * 4;
        #pragma unroll
        for (int nt = 0; nt < 4; nt++) {
            int col = col0 + nt * 16 + l15;
            float bv = bias ? bias[col] : 0.f;
            #pragma unroll
            for (int r = 0; r < 4; r++) {
                int row = rowb + r;
                if (row >= M) continue;
                size_t off = (size_t)row * N + col;
                float v = acc[mt][nt][r] + bv;
                if (EPI == 0) {
                    Cb[off] = f2b(v);
                } else if (EPI == 1) {
                    Cf[off] = v; Cb[off] = f2b(v);
                } else {
                    Cf[off] = v;
                }
            }
        }
    }
}

// ---------------- K pack: qkv K section -> ktb[h][tok][32] (contiguous per-head rows) ----
// Makes flash K-frag loads (16 rows x 64B) one contiguous 2KB block per wave.
__global__ __launch_bounds__(256) void kpack(const bf16s* __restrict__ qkvK,
                                             bf16s* __restrict__ ktb) {
    int tid = threadIdx.x;
    int tok = blockIdx.x * 8 + (tid >> 5);
    if (tok >= TTOK) return;
    int ch = (tid & 31) * 8;
    bf16x8 v = *(const bf16x8*)(qkvK + (size_t)tok * QKVS + ch);
    *(bf16x8*)(ktb + ((size_t)(ch >> 5) * TTOK + tok) * 32 + (ch & 31)) = v;
}

// ---------------- fused gate chain v1: 3 rounds of Wg1/Wg2/update (2-stage MFMA) --------
// Per block: 32 rows of e held in f32 REGISTERS (each wave owns a 64-col slice) + bf16
// mirrors of e/ctx/h in LDS. launch_bounds(256,3) caps VGPR ~170: kernel's live state is
// ~120 regs, the uncapped build allocated 256 (2 waves/SIMD + spills); 3 waves/SIMD
// matches the LDS limit (50.7KB -> 3 blocks/CU).
#define GLDS 264
__global__ __launch_bounds__(256, 3) void gatefuse(
    const bf16s* __restrict__ ctxob, bf16s* __restrict__ xb, const float* __restrict__ x,
    const bf16s* __restrict__ Wg1, const float* __restrict__ bg1,
    const bf16s* __restrict__ Wg2, const float* __restrict__ bg2, int M)
{
    __shared__ bf16s ebf[32 * GLDS], cxb[32 * GLDS], hbf[32 * GLDS];
    int tid = threadIdx.x, lane = tid & 63, wave = tid >> 6;
    int l15 = lane & 15, quad = lane >> 4;
    int r0 = blockIdx.x * 32;
    int col0 = wave * 64;

    // init: ebf (bf16 mirror) from xb; e32 (f32, reg) from x
    #pragma unroll
    for (int u = 0; u < 4; u++) {
        int idx = u * 256 + tid;
        int row = idx >> 5, ch = (idx & 31) * 8;
        *(bf16x8*)&ebf[row * GLDS + ch] =
            *(const bf16x8*)(xb + (size_t)min(r0 + row, M - 1) * HIDC + ch);
    }
    f32x4 e32[2][4];
    #pragma unroll
    for (int mt = 0; mt < 2; mt++)
        #pragma unroll
        for (int nt = 0; nt < 4; nt++)
            #pragma unroll
            for (int rr = 0; rr < 4; rr++) {
                int row = min(r0 + mt * 16 + quad * 4 + rr, M - 1);
                e32[mt][nt][rr] = x[(size_t)row * HIDC + col0 + nt * 16 + l15];
            }

    const bf16s* w1base = Wg1 + ((size_t)wave << 15) + l15 * 32 + quad * 8;  // nk=16
    const bf16s* w2base = Wg2 + ((size_t)wave << 14) + l15 * 32 + quad * 8;  // nk=8

    for (int r = 0; r < 3; r++) {
        __syncthreads();   // prev round's cxb reads + ebf writes complete
        const bf16s* crp = ctxob + (size_t)r * ((size_t)TTOK * HIDC);
        #pragma unroll
        for (int u = 0; u < 4; u++) {
            int idx = u * 256 + tid;
            int row = idx >> 5, ch = (idx & 31) * 8;
            *(bf16x8*)&cxb[row * GLDS + ch] =
                *(const bf16x8*)(crp + (size_t)min(r0 + row, M - 1) * HIDC + ch);
        }
        __syncthreads();

        f32x4 acc[2][4];
        bf16x8 aA[2], wA[4], aB[2], wB[4];

        // ---- Wg1: K=512 = [e(256) ++ ctx(256)], output h (relu, bf16 -> hbf) ----
        #pragma unroll
        for (int i = 0; i < 2; i++)
            #pragma unroll
            for (int j = 0; j < 4; j++) acc[i][j] = ZERO4;
        auto loadA1 = [&](bf16x8* af, int k32) {
            int kk = (k32 << 5) + quad * 8;
            if (kk < 256) {
                #pragma unroll
                for (int mt = 0; mt < 2; mt++)
                    af[mt] = *(const bf16x8*)&ebf[(mt * 16 + l15) * GLDS + kk];
            } else {
                #pragma unroll
                for (int mt = 0; mt < 2; mt++)
                    af[mt] = *(const bf16x8*)&cxb[(mt * 16 + l15) * GLDS + kk - 256];
            }
        };
        auto loadW1 = [&](bf16x8* wf, int k32) {
            const bf16s* p = w1base + ((size_t)k32 << 11);
            #pragma unroll
            for (int nt = 0; nt < 4; nt++)
                wf[nt] = *(const bf16x8*)(p + nt * 512);
        };
        loadA1(aA, 0); loadW1(wA, 0);
        for (int k32 = 0; k32 < 16; k32 += 2) {
            loadA1(aB, k32 + 1); loadW1(wB, k32 + 1);
            #pragma unroll
            for (int mt = 0; mt < 2; mt++)
                #pragma unroll
                for (int nt = 0; nt < 4; nt++)
                    acc[mt][nt] = MFMA16(aA[mt], wA[nt], acc[mt][nt]);
            if (k32 + 2 < 16) { loadA1(aA, k32 + 2); loadW1(wA, k32 + 2); }
            #pragma unroll
            for (int mt = 0; mt < 2; mt++)
                #pragma unroll
                for (int nt = 0; nt < 4; nt++)
                    acc[mt][nt] = MFMA16(aB[mt], wB[nt], acc[mt][nt]);
        }
        #pragma unroll
        for (int mt = 0; mt < 2; mt++)
            #pragma unroll
            for (int nt = 0; nt < 4; nt++)
                #pragma unroll
                for (int rr = 0; rr < 4; rr++) {
                    int row = mt * 16 + quad * 4 + rr;
                    int col = col0 + nt * 16 + l15;
                    hbf[row * GLDS + col] = f2b(fmaxf(acc[mt][nt][rr] + bg1[col], 0.f));
                }
        __syncthreads();   // hbf visible

        // ---- Wg2: K=256 from hbf; then e += sig(v) * ctx ----
        #pragma unroll
        for (int i = 0; i < 2; i++)
            #pragma unroll
            for (int j = 0; j < 4; j++) acc[i][j] = ZERO4;
        auto loadA2 = [&](bf16x8* af, int k32) {
            int kk = (k32 << 5) + quad * 8;
            #pragma unroll
            for (int mt = 0; mt < 2; mt++)
                af[mt] = *(const bf16x8*)&hbf[(mt * 16 + l15) * GLDS + kk];
        };
        auto loadW2 = [&](bf16x8* wf, int k32) {
            const bf16s* p = w2base + ((size_t)k32 << 11);
            #pragma unroll
            for (int nt = 0; nt < 4; nt++)
                wf[nt] = *(const bf16x8*)(p + nt * 512);
        };
        loadA2(aA, 0); loadW2(wA, 0);
        for (int k32 = 0; k32 < 8; k32 += 2) {
            loadA2(aB, k32 + 1); loadW2(wB, k32 + 1);
            #pragma unroll
            for (int mt = 0; mt < 2; mt++)
                #pragma unroll
                for (int nt = 0; nt < 4; nt++)
                    acc[mt][nt] = MFMA16(aA[mt], wA[nt], acc[mt][nt]);
            if (k32 + 2 < 8) { loadA2(aA, k32 + 2); loadW2(wA, k32 + 2); }
            #pragma unroll
            for (int mt = 0; mt < 2; mt++)
                #pragma unroll
                for (int nt = 0; nt < 4; nt++)
                    acc[mt][nt] = MFMA16(aB[mt], wB[nt], acc[mt][nt]);
        }
        #pragma unroll
        for (int mt = 0; mt < 2; mt++)
            #pragma unroll
            for (int nt = 0; nt < 4; nt++)
                #pragma unroll
                for (int rr = 0; rr < 4; rr++) {
                    int row = mt * 16 + quad * 4 + rr;
                    int col = col0 + nt * 16 + l15;
                    float v = acc[mt][nt][rr] + bg2[col];
                    float g = 1.f / (1.f + __expf(-v));
                    e32[mt][nt][rr] += g * b2f(cxb[row * GLDS + col]);
                }
        if (r < 2) {
            #pragma unroll
            for (int mt = 0; mt < 2; mt++)
                #pragma unroll
                for (int nt = 0; nt < 4; nt++)
                    #pragma unroll
                    for (int rr = 0; rr < 4; rr++) {
                        int row = mt * 16 + quad * 4 + rr;
                        int col = col0 + nt * 16 + l15;
                        ebf[row * GLDS + col] = f2b(e32[mt][nt][rr]);
                    }
        }
    }

    // final: write updated e (bf16 only; the f32 copy is dead downstream)
    #pragma unroll
    for (int mt = 0; mt < 2; mt++)
        #pragma unroll
        for (int nt = 0; nt < 4; nt++)
            #pragma unroll
            for (int rr = 0; rr < 4; rr++) {
                int row = r0 + mt * 16 + quad * 4 + rr;
                if (row < M)
                    xb[(size_t)row * HIDC + col0 + nt * 16 + l15] = f2b(e32[mt][nt][rr]);
            }
}

// ---------------- V transpose: [Mtok, stride VS] -> vtb [256][VTP] padded segments ----------
__global__ __launch_bounds__(256) void transpose_v(const bf16s* __restrict__ vsrc,
                                                   bf16s* __restrict__ vdst,
                                                   int Mtok, int Sk, int SkPad, int voff, int VS) {
    __shared__ bf16s t[64][72];
    int t0 = blockIdx.x * 64, d0 = blockIdx.y * 64;
    int tid = threadIdx.x;
    int lr = tid >> 2, lc = (tid & 3) * 16;
    if (t0 + lr < Mtok) {
        bf16x8 v0 = *(const bf16x8*)(vsrc + (size_t)(t0 + lr) * VS + d0 + lc);
        bf16x8 v1 = *(const bf16x8*)(vsrc + (size_t)(t0 + lr) * VS + d0 + lc + 8);
        *(bf16x8*)&t[lr][lc] = v0;
        *(bf16x8*)&t[lr][lc + 8] = v1;
    }
    __syncthreads();
    int dr = tid >> 2, tc = (tid & 3) * 16;
    #pragma unroll
    for (int u = 0; u < 16; u++) {
        int tok = t0 + tc + u;
        if (tok >= Mtok) break;
        int bidx = tok / Sk, s = tok - bidx * Sk;
        vdst[(size_t)(d0 + dr) * VTP + voff + bidx * SkPad + s] = t[tc + u][dr];
    }
}

// ---------------- flash v9: packed-K + 64 q-rows/wave + 4-way K-split ----------
__global__ __launch_bounds__(256) void flash8(const bf16s* __restrict__ qkv,
                                              const bf16s* __restrict__ vtb,
                                              const bf16s* __restrict__ ktb,
                                              bf16s* __restrict__ ctxall)
{
    __shared__ bf16s L[4][64 * 40];      // 20,480 B  P-tiles
    __shared__ float CMB[3][16][64];     // 12,288 B  combine (two passes: a0 then a1)
    __shared__ float CLS[3][4][64];      //  3,072 B  combine ls
    int bx = blockIdx.x;
    int sbg = bx >> 6, hb = bx & 63;
    int h = hb & 7, b = hb >> 3;
    int p = 0;
    while (sbg >= FP_SB0[p + 1]) p++;
    int wave = threadIdx.x >> 6, lane = threadIdx.x & 63;
    int l15 = lane & 15, quad = lane >> 4;
    int Sq = FP_SQ[p], Sk = FP_SK[p];
    bool ksp = (p < 3);
    int qrow0 = ksp ? (sbg - FP_SB0[p]) * 64
                    : ((sbg - FP_SB0[p]) * 4 + wave) * 64;
    if (qrow0 >= Sq) return;            // block-uniform when ksp (never taken there)
    int k0 = ksp ? wave * 784 : 0;
    int klim = ksp ? 784 : Sk;
    int qoff = FP_QOFF[p], koff = FP_KOFF[p];
    int voff = FP_VOFF[p], skp = FP_SKP[p];
    bf16s* ctxr = ctxall + (size_t)FP_R[p] * TTOK * HIDC;

    const bf16s* qrow = qkv + (size_t)(qoff + b * Sq) * QKVS + h * HDIM + quad * 8;
    bf16x8 qf[4];
    #pragma unroll
    for (int qi = 0; qi < 4; qi++)
        qf[qi] = *(const bf16x8*)(qrow + (size_t)min(qrow0 + qi * 16 + l15, Sq - 1) * QKVS);

    // packed K: wave's 16-row frag load = one contiguous 2KB block
    const bf16s* kp0 = ktb + ((size_t)h * TTOK + koff + b * Sk + k0 + l15) * 32 + quad * 8;
    const bf16s* kp16 = kp0 + 512;
    const bf16s* vp0 = vtb + (size_t)(h * HDIM + l15) * VTP + voff + b * skp + quad * 8;
    const bf16s* vp16 = vp0 + (size_t)16 * VTP;
    bf16s* Lw = L[wave];

    f32x4 a0[4], a1[4];   // a{dimhalf}[qi]
    float ls[4];
    #pragma unroll
    for (int qi = 0; qi < 4; qi++) { a0[qi] = ZERO4; a1[qi] = ZERO4; ls[qi] = 0.f; }
    int niter = (klim + 31) >> 5;

    bf16x8 kA0, kA1, vA0, vA1, kB0, kB1, vB0, vB1;

    auto loadKV = [&](bf16x8& kf0, bf16x8& kf1, bf16x8& vf0, bf16x8& vf1, int t) {
        size_t kb = (size_t)t << 10;
        kf0 = *(const bf16x8*)(kp0 + kb);
        kf1 = *(const bf16x8*)(kp16 + kb);
        vf0 = *(const bf16x8*)(vp0 + k0 + (t << 5));
        vf1 = *(const bf16x8*)(vp16 + k0 + (t << 5));
    };
    auto compute = [&](bf16x8 kf0, bf16x8 kf1, bf16x8 vf0, bf16x8 vf1, int t) {
        int kt = t << 5;
        f32x4 s0[4], s1[4];
        #pragma unroll
        for (int qi = 0; qi < 4; qi++) {
            s0[qi] = MFMA16(kf0, qf[qi], ZERO4);
            s1[qi] = MFMA16(kf1, qf[qi], ZERO4);
        }
        float p0[4][4], p1[4][4];
        #pragma unroll
        for (int qi = 0; qi < 4; qi++)
            #pragma unroll
            for (int r = 0; r < 4; r++) {
                p0[qi][r] = ex2(s0[qi][r]);
                p1[qi][r] = ex2(s1[qi][r]);
            }
        if (kt + 32 > klim) {  // tail: zero p for k >= klim (wave-uniform branch)
            int lim0 = klim - kt - quad * 4, lim1 = lim0 - 16;
            #pragma unroll
            for (int qi = 0; qi < 4; qi++)
                #pragma unroll
                for (int r = 0; r < 4; r++) {
                    if (r >= lim0) p0[qi][r] = 0.f;
                    if (r >= lim1) p1[qi][r] = 0.f;
                }
        }
        #pragma unroll
        for (int qi = 0; qi < 4; qi++) {
            #pragma unroll
            for (int r = 0; r < 4; r++) ls[qi] += p0[qi][r] + p1[qi][r];
            *(uint2*)&Lw[(qi * 16 + l15) * 40 + quad * 4] =
                make_uint2(cvtpk(p0[qi][0], p0[qi][1]), cvtpk(p0[qi][2], p0[qi][3]));
            *(uint2*)&Lw[(qi * 16 + l15) * 40 + 16 + quad * 4] =
                make_uint2(cvtpk(p1[qi][0], p1[qi][1]), cvtpk(p1[qi][2], p1[qi][3]));
        }
        #pragma unroll
        for (int qi = 0; qi < 4; qi++) {
            bf16x8 pb = *(const bf16x8*)&Lw[(qi * 16 + l15) * 40 + quad * 8];
            a0[qi] = MFMA16(vf0, pb, a0[qi]);
            a1[qi] = MFMA16(vf1, pb, a1[qi]);
        }
    };

    loadKV(kA0, kA1, vA0, vA1, 0);
    for (int t = 0; t < niter; t += 2) {
        if (t + 1 < niter) loadKV(kB0, kB1, vB0, vB1, t + 1);
        compute(kA0, kA1, vA0, vA1, t);
        if (t + 2 < niter) loadKV(kA0, kA1, vA0, vA1, t + 2);
        if (t + 1 < niter) compute(kB0, kB1, vB0, vB1, t + 1);
    }

    if (ksp) {
        // two-pass LDS combine across the 4 k-chunk waves (keeps LDS <= 36 KB)
        if (wave > 0) {
            #pragma unroll
            for (int qi = 0; qi < 4; qi++) {
                #pragma unroll
                for (int r = 0; r < 4; r++) CMB[wave - 1][qi * 4 + r][lane] = a0[qi][r];
                CLS[wave - 1][qi][lane] = ls[qi];
            }
        }
        __syncthreads();
        if (wave == 0) {
            #pragma unroll
            for (int w = 0; w < 3; w++)
                #pragma unroll
                for (int qi = 0; qi < 4; qi++) {
                    #pragma unroll
                    for (int r = 0; r < 4; r++) a0[qi][r] += CMB[w][qi * 4 + r][lane];
                    ls[qi] += CLS[w][qi][lane];
                }
        }
        __syncthreads();
        if (wave > 0) {
            #pragma unroll
            for (int qi = 0; qi < 4; qi++)
                #pragma unroll
                for (int r = 0; r < 4; r++) CMB[wave - 1][qi * 4 + r][lane] = a1[qi][r];
        }
        __syncthreads();
        if (wave > 0) return;
        #pragma unroll
        for (int w = 0; w < 3; w++)
            #pragma unroll
            for (int qi = 0; qi < 4; qi++)
                #pragma unroll
                for (int r = 0; r < 4; r++) a1[qi][r] += CMB[w][qi * 4 + r][lane];
    }

    #pragma unroll
    for (int qi = 0; qi < 4; qi++) {
        float l = ls[qi];
        l += __shfl_xor(l, 16); l += __shfl_xor(l, 32);
        float inv = 1.f / l;
        if (qrow0 + qi * 16 + l15 < Sq) {
            size_t o = (size_t)(qoff + b * Sq + qrow0 + qi * 16 + l15) * HIDC + h * HDIM;
            *(uint2*)(ctxr + o + quad * 4) =
                make_uint2(cvtpk(a0[qi][0] * inv, a0[qi][1] * inv),
                           cvtpk(a0[qi][2] * inv, a0[qi][3] * inv));
            *(uint2*)(ctxr + o + 16 + quad * 4) =
                make_uint2(cvtpk(a1[qi][0] * inv, a1[qi][1] * inv),
                           cvtpk(a1[qi][2] * inv, a1[qi][3] * inv));
        }
    }
}

// ---------------- CECM: pooled mean partials over all scales ----------------
__global__ __launch_bounds__(256) void pool2(const bf16s* __restrict__ xb,
                                             float* __restrict__ partial) {
    int chunk = blockIdx.x, b = blockIdx.y, i = blockIdx.z;
    int c = threadIdx.x;
    int S = DC_S[i];
    int len = (S + 31) / 32;
    int s0 = chunk * len, s1 = min(S, s0 + len);
    float acc = 0.f;
    const bf16s* base = xb + (size_t)(DC_BOFF[i] + b * S) * HIDC + c;
    for (int s = s0; s < s1; s++) acc += b2f(base[(size_t)s * HIDC]);
    partial[(size_t)((i * NB + b) * 32 + chunk) * HIDC + c] = acc;
}

// ---------------- CECM: kernel generator MLP (all scales) ----------------
__global__ __launch_bounds__(256) void kgen2(
    const float* __restrict__ partial,
    const float* __restrict__ Wcp, const float* __restrict__ bcp,
    const float* __restrict__ Wkg1, const float* __restrict__ bkg1,
    const float* __restrict__ Wkg2, const float* __restrict__ bkg2,
    float* __restrict__ kern)
{
    __shared__ float pl[256], cv[256], h1[512];
    int b = blockIdx.x, i = blockIdx.y, t = threadIdx.x;
    float invS = 1.f / (float)DC_S[i];
    const float* pb = partial + (size_t)((i * NB + b) * 32) * HIDC;
    float s = 0.f;
    for (int jc = 0; jc < 32; jc++) s += pb[(size_t)jc * HIDC + t];
    pl[t] = s * invS;
    __syncthreads();
    float a = bcp[t];
    for (int k = 0; k < 256; k++) a += Wcp[t * 256 + k] * pl[k];
    cv[t] = fmaxf(a, 0.f);
    __syncthreads();
    for (int r = t; r < 512; r += 256) {
        float a2 = bkg1[r];
        for (int k = 0; k < 256; k++) a2 += Wkg1[r * 256 + k] * cv[k];
        h1[r] = fmaxf(a2, 0.f);
    }
    __syncthreads();
    if (t < 72) {
        float a3 = bkg2[t];
        for (int k = 0; k < 512; k++) a3 += Wkg2[t * 512 + k] * h1[k];
        kern[(i * NB + b) * 72 + t] = a3;
    }
}

// ---------------- CECM: fused dynamic depthwise 3x3 over all scales ----------------
__global__ __launch_bounds__(256) void dwconv2(const bf16s* __restrict__ xtb,
                                               const float* __restrict__ kern,
                                               bf16s* __restrict__ y) {
    int tok = blockIdx.x;
    int i = (tok >= DC_BOFF[1]) + (tok >= DC_BOFF[2]) + (tok >= DC_BOFF[3]);
    int S = DC_S[i], W = DC_HW[i];
    int local = tok - DC_BOFF[i];
    int b = local / S, s = local - b * S;
    int hh = s / W, ww = s - hh * W;
    int c = threadIdx.x;
    const float* kb = kern + (i * NB + b) * 72 + (c >> 5) * 9;
    const bf16s* xbase = xtb + (size_t)(DC_BOFF[i] + b * S) * HIDC + c;
    float acc = 0.f;
    #pragma unroll
    for (int ky = 0; ky < 3; ky++) {
        int hy = hh + ky - 1;
        if (hy < 0 || hy >= W) continue;
        #pragma unroll
        for (int kx = 0; kx < 3; kx++) {
            int wx = ww + kx - 1;
            if (wx < 0 || wx >= W) continue;
            acc += kb[ky * 3 + kx] * b2f(xbase[(size_t)(hy * W + wx) * HIDC]);
        }
    }
    y[(size_t)tok * HIDC + c] = f2b(acc);
}

// ---------------- BN stats v2: 512 blocks, float4 loads, LDS row-group reduce ----------
__global__ __launch_bounds__(256) void bn1(const float* __restrict__ yo,
                                           float* __restrict__ bnp) {
    __shared__ float red[4][64][8];
    int chunk = blockIdx.x, i = blockIdx.y, t = threadIdx.x;
    int rg = t >> 6, cq = (t & 63) * 4;
    int Nrows = NB * DC_S[i];
    const float* base = yo + (size_t)DC_BOFF[i] * HIDC + cq;
    f32x4 s = ZERO4, ss = ZERO4;
    for (int r = chunk * 4 + rg; r < Nrows; r += BN1_CH * 4) {
        f32x4 v = *(const f32x4*)(base + (size_t)r * HIDC);
        s += v; ss += v * v;
    }
    #pragma unroll
    for (int j = 0; j < 4; j++) { red[rg][t & 63][j] = s[j]; red[rg][t & 63][4 + j] = ss[j]; }
    __syncthreads();
    if (t < 64) {
        #pragma unroll
        for (int j = 0; j < 4; j++) {
            float a = red[0][t][j] + red[1][t][j] + red[2][t][j] + red[3][t][j];
            float b = red[0][t][4 + j] + red[1][t][4 + j] + red[2][t][4 + j] + red[3][t][4 + j];
            bnp[(size_t)(i * BN1_CH + chunk) * 512 + t * 4 + j] = a;
            bnp[(size_t)(i * BN1_CH + chunk) * 512 + 256 + t * 4 + j] = b;
        }
    }
}
__global__ __launch_bounds__(256) void bn2(const float* __restrict__ bnp,
                                           float* __restrict__ stat) {
    int i = blockIdx.x, c = threadIdx.x;
    float s = 0.f, ss = 0.f;
    for (int ch = 0; ch < BN1_CH; ch++) {
        s += bnp[(size_t)(i * BN1_CH + ch) * 512 + c];
        ss += bnp[(size_t)(i * BN1_CH + ch) * 512 + 256 + c];
    }
    float inv = 1.f / (float)(NB * DC_S[i]);
    float mu = s * inv;
    float var = fmaxf(ss * inv - mu * mu, 0.f);
    stat[i * 512 + c] = mu;
    stat[i * 512 + 256 + c] = rsqrtf(var + 1e-5f);
}

// ---------------- fused final output (tiled transpose), all scales ----------------
__global__ __launch_bounds__(256) void final2(const bf16s* __restrict__ xtb,
                                              const float* __restrict__ yo,
                                              const float* __restrict__ stat,
                                              const float* __restrict__ gamma,
                                              const float* __restrict__ beta,
                                              float* __restrict__ out) {
    __shared__ float tile[64][65];
    int bx = blockIdx.x;
    int i = (bx >= DC_FOS[1]) + (bx >= DC_FOS[2]) + (bx >= DC_FOS[3]);
    int S = DC_S[i];
    int s0 = (bx - DC_FOS[i]) * 64;
    int cstrip = blockIdx.y, b = blockIdx.z;
    int g = threadIdx.x >> 6, sl = threadIdx.x & 63;
    {
        int c = cstrip * 64 + sl;
        float mu = stat[i * 512 + c], rstd = stat[i * 512 + 256 + c];
        float ga = gamma[c], be = beta[c];
        size_t rbase = (size_t)(DC_BOFF[i] + b * S) * HIDC + c;
        #pragma unroll
        for (int u = 0; u < 16; u++) {
            int s = s0 + g * 16 + u;
            if (s < S) {
                size_t r = rbase + (size_t)s * HIDC;
                tile[g * 16 + u][sl] = b2f(xtb[r]) + (yo[r] - mu) * rstd * ga + be;
            }
        }
    }
    __syncthreads();
    {
        int s = s0 + sl;
        if (s < S) {
            #pragma unroll
            for (int cs = 0; cs < 16; cs++) {
                int cl = g * 16 + cs;
                out[((size_t)(b * HIDC + cstrip * 64 + cl)) * STOT + DC_GOFF[i] + s] = tile[sl][cl];
            }
        }
    }
}

// ---------------- host helpers ----------------
static inline void gemm_launch(hipStream_t st, const bf16s* A, const bf16s* A2,
                               const bf16s* W, const float* bias,
                               float* Cf, bf16s* Cb, const bf16s* Gaux,
                               int M, int N, int K, int K1, int epi) {
    dim3 grid(N / 128, (M + 63) / 64), blk(256);
    switch (epi) {
        case 0: gemm3<0><<<grid, blk, 0, st>>>(A, A2, W, bias, Cf, Cb, Gaux, M, N, K, K1); break;
        case 1: gemm3<1><<<grid, blk, 0, st>>>(A, A2, W, bias, Cf, Cb, Gaux, M, N, K, K1); break;
        default: gemm3<4><<<grid, blk, 0, st>>>(A, A2, W, bias, Cf, Cb, Gaux, M, N, K, K1); break;
    }
}

extern "C" void kernel_launch(void* const* d_in, const int* in_sizes, int n_in,
                              void* d_out, int out_size, void* d_ws, size_t ws_size,
                              hipStream_t stream) {
    typedef const float* fp;
    fp f[4]  = {(fp)d_in[0], (fp)d_in[3], (fp)d_in[6], (fp)d_in[9]};
    fp Wp[4] = {(fp)d_in[1], (fp)d_in[4], (fp)d_in[7], (fp)d_in[10]};
    fp bp[4] = {(fp)d_in[2], (fp)d_in[5], (fp)d_in[8], (fp)d_in[11]};
    fp Wq = (fp)d_in[12], Wk = (fp)d_in[13], Wv = (fp)d_in[14], Wo = (fp)d_in[15];
    fp Wg1 = (fp)d_in[16], Wg2 = (fp)d_in[17], Wcp = (fp)d_in[18];
    fp Wkg1 = (fp)d_in[19], Wkg2 = (fp)d_in[20], Wit = (fp)d_in[21], Wot = (fp)d_in[22];
    fp bq = (fp)d_in[23], bk = (fp)d_in[24], bv = (fp)d_in[25], bo = (fp)d_in[26];
    fp bg1 = (fp)d_in[27], bg2 = (fp)d_in[28], bcp = (fp)d_in[29];
    fp bkg1 = (fp)d_in[30], bkg2 = (fp)d_in[31], bit = (fp)d_in[32], bot = (fp)d_in[33];
    fp gamma = (fp)d_in[34], beta = (fp)d_in[35];
    float* out = (float*)d_out;

    const size_t NT = (size_t)TTOK * HIDC;   // 8,529,920

    // ---- workspace carve ----
    float* x     = (float*)d_ws;               // e f32; phase 4: yo aliases x
    bf16s* xb    = (bf16s*)(x + NT);           // e bf16 mirror
    bf16s* qkvb  = xb + NT;                    // [TTOK, 768]; dead after flash -> ctxob2
    bf16s* vtb   = qkvb + (size_t)TTOK * QKVS; // [256][VTP] (zero-filled)
    bf16s* ctxall= vtb + (size_t)HIDC * VTP;   // 3 x [TTOK,256] flash ctx
    bf16s* ctxob = ctxall + 3 * NT;            // repurposed: ktb (packed K)
    float* partial = (float*)(ctxob + 3 * NT);
    float* kern    = partial + 4 * NB * 32 * HIDC;
    float* bnp     = kern + 4 * NB * 72;
    float* bnstat  = bnp + 4 * 32 * 512;
    float* bqkv    = bnstat + 4 * 512;         // 768
    bf16s* wseg    = (bf16s*)(bqkv + 768);
    // aliases
    bf16s* atmp = ctxall;                      // phase-1 scratch
    bf16s* hb   = ctxall;                      // dwconv out (phase 4; ctxall dead then)
    bf16s* xtb  = ctxall + NT;                 // Wit out (phase 4)
    float* yo   = x;                           // phase-4 Wot out (e f32 dead)
    float* bnp2 = partial;                     // bn1 partials reuse `partial`
    bf16s* ktb  = ctxob;                       // packed K [8][TTOK][32]
    bf16s* ctxob2 = qkvb;                      // Wo out: qkvb region (3NT exact), dead after flash

    // weight pointers in wseg (all bf16 weights stored SWIZZLED)
    bf16s* wpb[4]; size_t wo_ = 0;
    for (int i = 0; i < 4; i++) { wpb[i] = wseg + wo_; wo_ += (size_t)HIDC * D_IN[i]; }
    bf16s* wqkvb = wseg + wo_; wo_ += (size_t)QKVS * 256;
    bf16s* wob  = wseg + wo_; wo_ += 65536;
    bf16s* wg1b = wseg + wo_; wo_ += 131072;
    bf16s* wg2b = wseg + wo_; wo_ += 65536;
    bf16s* witb = wseg + wo_; wo_ += 65536;
    bf16s* wotb = wseg + wo_; wo_ += 65536;

    // ---- fused weight conversion + swizzle (Wq/bq pre-scaled by 1/sqrt(32)*log2e) ----
    {
        CvtArgs ca;
        const float* srcs[15] = {Wp[0], Wp[1], Wp[2], Wp[3], Wq, Wk, Wv, Wo, Wg1, Wg2,
                                 Wit, Wot, bq, bk, bv};
        void* dsts[15] = {wpb[0], wpb[1], wpb[2], wpb[3], wqkvb, wqkvb + 65536,
                          wqkvb + 131072, wob, wg1b, wg2b, witb, wotb,
                          bqkv, bqkv + 256, bqkv + 512};
        int ns[15] = {16384, 32768, 65536, 131072, 65536, 65536, 65536, 65536, 131072,
                      65536, 65536, 65536, 256, 256, 256};
        int modes[15] = {0, 0, 0, 0, 1, 0, 0, 0, 0, 0, 0, 0, 3, 2, 2};
        int Ks[15] = {64, 128, 256, 512, 256, 256, 256, 256, 512, 256, 256, 256, 0, 0, 0};
        int total = 0;
        for (int k = 0; k < 15; k++) { ca.src[k] = srcs[k]; ca.dst[k] = dsts[k];
                                       ca.n[k] = ns[k]; ca.mode[k] = modes[k];
                                       ca.K[k] = Ks[k]; total += ns[k]; }
        cvt_all<<<dim3((total + 255) / 256), dim3(256), 0, stream>>>(ca, total);
    }
    // zero vtb so pad regions / unguarded tail reads are finite
    hipMemsetAsync(vtb, 0, (size_t)HIDC * VTP * sizeof(bf16s), stream);

    // ---- phase 1: per-scale 1x1 projection -> x (f32) + xb (bf16) ----
    for (int i = 0; i < 4; i++) {
        int S = S_SZ[i], D = D_IN[i], M = NB * S;
        transpose_f2<<<dim3((S + 31) / 32, D / 32, NB), dim3(256), 0, stream>>>(f[i], atmp, D, S);
        gemm_launch(stream, atmp, nullptr, wpb[i], bp[i],
                    x + (size_t)BOFF[i] * HIDC, xb + (size_t)BOFF[i] * HIDC, nullptr,
                    M, HIDC, D, D, 1);
    }

    // ---- phase 2: merged QKV GEMM + V transpose + K pack ----
    gemm_launch(stream, xb, nullptr, wqkvb, bqkv, nullptr, qkvb, nullptr, TTOK, QKVS, 256, 256, 0);
    for (int j = 0; j < 4; j++) {
        int Mtok = NB * S_SZ[j];
        transpose_v<<<dim3((Mtok + 63) / 64, 4), dim3(256), 0, stream>>>(
            qkvb + 512 + (size_t)BOFF[j] * QKVS, vtb, Mtok, S_SZ[j], SKPAD_H[j], VWOFF_H[j], QKVS);
    }
    kpack<<<dim3((TTOK + 7) / 8), dim3(256), 0, stream>>>(qkvb + 256, ktb);

    // ---- phase 3: flash, batched Wo (out -> dead qkvb region), fused gate chain ----
    flash8<<<dim3(69 * 64), dim3(256), 0, stream>>>(qkvb, vtb, ktb, ctxall);
    gemm_launch(stream, ctxall, nullptr, wob, bo, nullptr, ctxob2, nullptr, 3 * TTOK, HIDC, 256, 256, 0);
    gatefuse<<<dim3((TTOK + 31) / 32), dim3(256), 0, stream>>>(
        ctxob2, xb, x, wg1b, bg1, wg2b, bg2, TTOK);

    // ---- phase 4: CECM fused across scales ----
    pool2<<<dim3(32, NB, 4), dim3(256), 0, stream>>>(xb, partial);
    kgen2<<<dim3(NB, 4), dim3(256), 0, stream>>>(partial, Wcp, bcp, Wkg1, bkg1, Wkg2, bkg2, kern);
    gemm_launch(stream, xb, nullptr, witb, bit, nullptr, xtb, nullptr, TTOK, HIDC, 256, 256, 0);
    dwconv2<<<dim3(TTOK), dim3(256), 0, stream>>>(xtb, kern, hb);
    gemm_launch(stream, hb, nullptr, wotb, bot, yo, nullptr, nullptr, TTOK, HIDC, 256, 256, 4);
    bn1<<<dim3(BN1_CH, 4), dim3(256), 0, stream>>>(yo, bnp2);
    bn2<<<dim3(4), dim3(256), 0, stream>>>(bnp2, bnstat);
    final2<<<dim3(67, 4, NB), dim3(256), 0, stream>>>(xtb, yo, bnstat, gamma, beta, out);
}

// Round 14
// 846.761 us; speedup vs baseline: 1.3039x; 1.3039x over previous
//
#include <hip/hip_runtime.h>
#include <hip/hip_bf16.h>
#include <cstddef>

// ---------------- constants ----------------
#define NB 8
#define HIDC 256
#define NHEAD 8
#define HDIM 32
#define TTOK 33320
#define STOT 4165
#define VTP 33440
#define QKVS 768          // merged qkv row stride
// 1/sqrt(32) * log2(e): fold softmax scale AND exp->exp2 conversion into Wq/bq
#define QSC2 0.2550348757f
#define BN1_CH 128        // bn1 chunks per scale (512 blocks total)

static const int H_SZ[4]   = {56, 28, 14, 7};
static const int S_SZ[4]   = {3136, 784, 196, 49};
static const int D_IN[4]   = {64, 128, 256, 512};
static const int BOFF[4]   = {0, 25088, 31360, 32928};
static const int SKPAD_H[4]= {3136, 784, 200, 56};
static const int VWOFF_H[4]= {0, 25088, 31360, 32960};

__constant__ int DC_S[4]     = {3136, 784, 196, 49};
__constant__ int DC_HW[4]    = {56, 28, 14, 7};
__constant__ int DC_BOFF[4]  = {0, 25088, 31360, 32928};
__constant__ int DC_GOFF[4]  = {0, 3136, 3920, 4116};
__constant__ int DC_FOS[4]   = {0, 49, 62, 66};   // final_out 64-token block starts (total 67)

// flash pair tables, sorted by Sk desc (long waves dispatch first).
// Pairs 0-2 (Sk=3136): K-SPLIT blocks = 64 q rows, 4 waves x 784-key chunks, LDS combine;
//   nblk = ceil(Sq/64).
// Pairs 3-11: block = 4 independent waves x 64 q rows; nblk = ceil(Sq/256).
__constant__ int FP_SQ[12]   = {784,196,49,3136,196,49,3136,784,49,3136,784,196};
__constant__ int FP_SK[12]   = {3136,3136,3136,784,784,784,196,196,196,49,49,49};
__constant__ int FP_QOFF[12] = {25088,31360,32928,0,31360,32928,0,25088,32928,0,25088,31360};
__constant__ int FP_KOFF[12] = {0,0,0,25088,25088,25088,31360,31360,31360,32928,32928,32928};
__constant__ int FP_VOFF[12] = {0,0,0,25088,25088,25088,31360,31360,31360,32960,32960,32960};
__constant__ int FP_SKP[12]  = {3136,3136,3136,784,784,784,200,200,200,56,56,56};
__constant__ int FP_R[12]    = {0,0,0,0,1,1,1,1,2,2,2,2};
__constant__ int FP_SB0[13]  = {0,13,17,18,31,32,33,46,50,51,64,68,69};

typedef short bf16s;
typedef bf16s bf16x8 __attribute__((ext_vector_type(8)));
typedef float f32x4 __attribute__((ext_vector_type(4)));

// fast f32->bf16 (round half up; |err| == RNE ulp bound, no NaN/inf in data)
static __device__ inline bf16s f2b(float f) {
    return (bf16s)((__float_as_uint(f) + 0x8000u) >> 16);
}
static __device__ inline float b2f(bf16s s) {
    return __uint_as_float(((unsigned)(unsigned short)s) << 16);
}
// pack two f32 -> two bf16 in one dword (single HW instr, RNE; a in low half)
static __device__ inline unsigned cvtpk(float a, float b) {
    unsigned r;
    asm("v_cvt_pk_bf16_f32 %0, %1, %2" : "=v"(r) : "v"(a), "v"(b));
    return r;
}
static __device__ inline float ex2(float x) {
#if __has_builtin(__builtin_amdgcn_exp2f)
    return __builtin_amdgcn_exp2f(x);
#else
    return exp2f(x);
#endif
}
#define MFMA16(a, b, c) __builtin_amdgcn_mfma_f32_16x16x32_bf16(a, b, c, 0, 0, 0)
#define ZERO4 ((f32x4){0.f, 0.f, 0.f, 0.f})

// ---------------- fused weight conversion + W swizzle ----------------
// Swizzled weight layout for gemm3: for (n,k) with n-block c64=n>>6, k-block k32=k>>5:
//   dst = ((c64*(K/32) + k32)*4 + nt)*512 + l15*32 + q*8 + j
// where nt=(n>>4)&3, l15=n&15, q=(k>>3)&3, j=k&7.  One wave W-frag load = 1KB contiguous.
struct CvtArgs {
    const float* src[15];
    void* dst[15];
    int n[15];
    int mode[15];   // 0: bf16 swizzled  1: bf16 swizzled *QSC2  2: f32 copy  3: f32*QSC2
    int K[15];      // weight K (pow2) for swizzle modes
};
__global__ __launch_bounds__(256) void cvt_all(CvtArgs a, int total) {
    int idx = blockIdx.x * 256 + threadIdx.x;
    if (idx >= total) return;
    int seg = 0, off = idx;
    while (off >= a.n[seg]) { off -= a.n[seg]; seg++; }
    float v = a.src[seg][off];
    int m = a.mode[seg];
    if (m == 1 || m == 3) v *= QSC2;
    if (m <= 1) {
        int K = a.K[seg];
        int kz = __builtin_ctz(K);
        int n = off >> kz, k = off & (K - 1);
        int c64 = n >> 6, nt = (n >> 4) & 3, l15 = n & 15;
        int k32 = k >> 5, q = (k >> 3) & 3, j = k & 7;
        int dst = (((c64 * (K >> 5) + k32) * 4 + nt) << 9) + l15 * 32 + q * 8 + j;
        ((bf16s*)a.dst[seg])[dst] = f2b(v);
    } else {
        ((float*)a.dst[seg])[off] = v;
    }
}

// ---------------- tiled transpose f [B,D,S] f32 -> A [B*S, D] bf16 ----------------
__global__ __launch_bounds__(256) void transpose_f2(const float* __restrict__ f,
                                                    bf16s* __restrict__ A, int D, int S) {
    __shared__ float t[32][33];
    int s0 = blockIdx.x * 32, d0 = blockIdx.y * 32, b = blockIdx.z;
    int sl = threadIdx.x & 31, dl = threadIdx.x >> 5;
    #pragma unroll
    for (int dd = 0; dd < 32; dd += 8) {
        int s = s0 + sl;
        t[dl + dd][sl] = (s < S) ? f[((size_t)(b * D + d0 + dl + dd)) * S + s] : 0.f;
    }
    __syncthreads();
    int dc = threadIdx.x & 31, sg = threadIdx.x >> 5;
    #pragma unroll
    for (int ss = 0; ss < 32; ss += 8) {
        int s = s0 + sg + ss;
        if (s < S) A[((size_t)(b * S + s)) * D + d0 + dc] = f2b(t[dc][sg + ss]);
    }
}

// ---------------- MFMA GEMM v4: 64x128 block tile ----------------
// block 256 = 4 waves (2 row-groups x 2 col-groups); wave tile 32x64; block tile 64x128.
// EPI 0: bf16->Cb | 1: f32->Cf + bf16->Cb | 4: f32->Cf
template <int EPI>
__global__ __launch_bounds__(256) void gemm3(
    const bf16s* __restrict__ A, const bf16s* __restrict__ A2,
    const bf16s* __restrict__ W, const float* __restrict__ bias,
    float* __restrict__ Cf, bf16s* __restrict__ Cb, const bf16s* __restrict__ Gaux,
    int M, int N, int K, int K1)
{
    int tid = threadIdx.x, lane = tid & 63, wave = tid >> 6;
    int l15 = lane & 15, quad = lane >> 4;
    int row0 = blockIdx.y * 64 + (wave >> 1) * 32;
    int col0 = blockIdx.x * 128 + (wave & 1) * 64;
    int K2 = K - K1;
    int nk = K >> 5;
    int c64 = (blockIdx.x << 1) + (wave & 1);
    const bf16s* wbase = W + (size_t)c64 * ((size_t)nk << 11) + l15 * 32 + quad * 8;
    int ra[2];
    #pragma unroll
    for (int mt = 0; mt < 2; mt++) ra[mt] = min(row0 + mt * 16 + l15, M - 1);

    f32x4 acc[2][4];
    #pragma unroll
    for (int i = 0; i < 2; i++)
        #pragma unroll
        for (int j = 0; j < 4; j++) acc[i][j] = ZERO4;

    bf16x8 aA[2], wA[4], aB[2], wB[4];

    auto loadA = [&](bf16x8* af, int k32) {
        int kk = (k32 << 5) + quad * 8;
        if (kk < K1) {
            #pragma unroll
            for (int mt = 0; mt < 2; mt++)
                af[mt] = *(const bf16x8*)(A + (size_t)ra[mt] * K1 + kk);
        } else {
            int k2 = kk - K1;
            #pragma unroll
            for (int mt = 0; mt < 2; mt++)
                af[mt] = *(const bf16x8*)(A2 + (size_t)ra[mt] * K2 + k2);
        }
    };
    auto loadW = [&](bf16x8* wf, int k32) {
        const bf16s* p = wbase + ((size_t)k32 << 11);
        #pragma unroll
        for (int nt = 0; nt < 4; nt++)
            wf[nt] = *(const bf16x8*)(p + nt * 512);
    };

    loadA(aA, 0); loadW(wA, 0);
    for (int k32 = 0; k32 < nk; k32 += 2) {
        loadA(aB, k32 + 1); loadW(wB, k32 + 1);
        #pragma unroll
        for (int mt = 0; mt < 2; mt++)
            #pragma unroll
            for (int nt = 0; nt < 4; nt++)
                acc[mt][nt] = MFMA16(aA[mt], wA[nt], acc[mt][nt]);
        if (k32 + 2 < nk) { loadA(aA, k32 + 2); loadW(wA, k32 + 2); }
        #pragma unroll
        for (int mt = 0; mt < 2; mt++)
            #pragma unroll
            for (int nt = 0; nt < 4; nt++)
                acc[mt][nt] = MFMA16(aB[mt], wB[nt], acc[mt][nt]);
    }

    #pragma unroll
    for (int mt = 0; mt < 2; mt++) {
        int rowb = row0 + mt * 16 + quad * 4;
        #pragma unroll
        for (int nt = 0; nt < 4; nt++) {
            int col = col0 + nt * 16 + l15;
            float bv = bias ? bias[col] : 0.f;
            #pragma unroll
            for (int r = 0; r < 4; r++) {
                int row = rowb + r;
                if (row >= M) continue;
                size_t off = (size_t)row * N + col;
                float v = acc[mt][nt][r] + bv;
                if (EPI == 0) {
                    Cb[off] = f2b(v);
                } else if (EPI == 1) {
                    Cf[off] = v; Cb[off] = f2b(v);
                } else {
                    Cf[off] = v;
                }
            }
        }
    }
}

// ---------------- K pack: qkv K section -> ktb[h][tok][32] (contiguous per-head rows) ----
// Makes flash K-frag loads (16 rows x 64B) one contiguous 2KB block per wave.
__global__ __launch_bounds__(256) void kpack(const bf16s* __restrict__ qkvK,
                                             bf16s* __restrict__ ktb) {
    int tid = threadIdx.x;
    int tok = blockIdx.x * 8 + (tid >> 5);
    if (tok >= TTOK) return;
    int ch = (tid & 31) * 8;
    bf16x8 v = *(const bf16x8*)(qkvK + (size_t)tok * QKVS + ch);
    *(bf16x8*)(ktb + ((size_t)(ch >> 5) * TTOK + tok) * 32 + (ch & 31)) = v;
}

// ---------------- fused gate chain v1: 3 rounds of Wg1/Wg2/update (2-stage MFMA) --------
// Per block: 32 rows of e held in f32 REGISTERS (each wave owns a 64-col slice) + bf16
// mirrors of e/ctx/h in LDS (stride 264 kills bank conflicts). Weights read swizzled
// from L2. NOTE: uncapped launch bounds — (256,3) made the allocator pin 84 VGPRs and
// spill ~1GB (r13); 3-stage Wo fusion hit the 256-VGPR cap and spilled (r11). This
// 2-stage / uncapped config is the verified optimum (152us).
#define GLDS 264
__global__ __launch_bounds__(256) void gatefuse(
    const bf16s* __restrict__ ctxob, bf16s* __restrict__ xb, const float* __restrict__ x,
    const bf16s* __restrict__ Wg1, const float* __restrict__ bg1,
    const bf16s* __restrict__ Wg2, const float* __restrict__ bg2, int M)
{
    __shared__ bf16s ebf[32 * GLDS], cxb[32 * GLDS], hbf[32 * GLDS];
    int tid = threadIdx.x, lane = tid & 63, wave = tid >> 6;
    int l15 = lane & 15, quad = lane >> 4;
    int r0 = blockIdx.x * 32;
    int col0 = wave * 64;

    // init: ebf (bf16 mirror) from xb; e32 (f32, reg) from x
    #pragma unroll
    for (int u = 0; u < 4; u++) {
        int idx = u * 256 + tid;
        int row = idx >> 5, ch = (idx & 31) * 8;
        *(bf16x8*)&ebf[row * GLDS + ch] =
            *(const bf16x8*)(xb + (size_t)min(r0 + row, M - 1) * HIDC + ch);
    }
    f32x4 e32[2][4];
    #pragma unroll
    for (int mt = 0; mt < 2; mt++)
        #pragma unroll
        for (int nt = 0; nt < 4; nt++)
            #pragma unroll
            for (int rr = 0; rr < 4; rr++) {
                int row = min(r0 + mt * 16 + quad * 4 + rr, M - 1);
                e32[mt][nt][rr] = x[(size_t)row * HIDC + col0 + nt * 16 + l15];
            }

    const bf16s* w1base = Wg1 + ((size_t)wave << 15) + l15 * 32 + quad * 8;  // nk=16
    const bf16s* w2base = Wg2 + ((size_t)wave << 14) + l15 * 32 + quad * 8;  // nk=8

    for (int r = 0; r < 3; r++) {
        __syncthreads();   // prev round's cxb reads + ebf writes complete
        const bf16s* crp = ctxob + (size_t)r * ((size_t)TTOK * HIDC);
        #pragma unroll
        for (int u = 0; u < 4; u++) {
            int idx = u * 256 + tid;
            int row = idx >> 5, ch = (idx & 31) * 8;
            *(bf16x8*)&cxb[row * GLDS + ch] =
                *(const bf16x8*)(crp + (size_t)min(r0 + row, M - 1) * HIDC + ch);
        }
        __syncthreads();

        f32x4 acc[2][4];
        bf16x8 aA[2], wA[4], aB[2], wB[4];

        // ---- Wg1: K=512 = [e(256) ++ ctx(256)], output h (relu, bf16 -> hbf) ----
        #pragma unroll
        for (int i = 0; i < 2; i++)
            #pragma unroll
            for (int j = 0; j < 4; j++) acc[i][j] = ZERO4;
        auto loadA1 = [&](bf16x8* af, int k32) {
            int kk = (k32 << 5) + quad * 8;
            if (kk < 256) {
                #pragma unroll
                for (int mt = 0; mt < 2; mt++)
                    af[mt] = *(const bf16x8*)&ebf[(mt * 16 + l15) * GLDS + kk];
            } else {
                #pragma unroll
                for (int mt = 0; mt < 2; mt++)
                    af[mt] = *(const bf16x8*)&cxb[(mt * 16 + l15) * GLDS + kk - 256];
            }
        };
        auto loadW1 = [&](bf16x8* wf, int k32) {
            const bf16s* p = w1base + ((size_t)k32 << 11);
            #pragma unroll
            for (int nt = 0; nt < 4; nt++)
                wf[nt] = *(const bf16x8*)(p + nt * 512);
        };
        loadA1(aA, 0); loadW1(wA, 0);
        for (int k32 = 0; k32 < 16; k32 += 2) {
            loadA1(aB, k32 + 1); loadW1(wB, k32 + 1);
            #pragma unroll
            for (int mt = 0; mt < 2; mt++)
                #pragma unroll
                for (int nt = 0; nt < 4; nt++)
                    acc[mt][nt] = MFMA16(aA[mt], wA[nt], acc[mt][nt]);
            if (k32 + 2 < 16) { loadA1(aA, k32 + 2); loadW1(wA, k32 + 2); }
            #pragma unroll
            for (int mt = 0; mt < 2; mt++)
                #pragma unroll
                for (int nt = 0; nt < 4; nt++)
                    acc[mt][nt] = MFMA16(aB[mt], wB[nt], acc[mt][nt]);
        }
        #pragma unroll
        for (int mt = 0; mt < 2; mt++)
            #pragma unroll
            for (int nt = 0; nt < 4; nt++)
                #pragma unroll
                for (int rr = 0; rr < 4; rr++) {
                    int row = mt * 16 + quad * 4 + rr;
                    int col = col0 + nt * 16 + l15;
                    hbf[row * GLDS + col] = f2b(fmaxf(acc[mt][nt][rr] + bg1[col], 0.f));
                }
        __syncthreads();   // hbf visible

        // ---- Wg2: K=256 from hbf; then e += sig(v) * ctx ----
        #pragma unroll
        for (int i = 0; i < 2; i++)
            #pragma unroll
            for (int j = 0; j < 4; j++) acc[i][j] = ZERO4;
        auto loadA2 = [&](bf16x8* af, int k32) {
            int kk = (k32 << 5) + quad * 8;
            #pragma unroll
            for (int mt = 0; mt < 2; mt++)
                af[mt] = *(const bf16x8*)&hbf[(mt * 16 + l15) * GLDS + kk];
        };
        auto loadW2 = [&](bf16x8* wf, int k32) {
            const bf16s* p = w2base + ((size_t)k32 << 11);
            #pragma unroll
            for (int nt = 0; nt < 4; nt++)
                wf[nt] = *(const bf16x8*)(p + nt * 512);
        };
        loadA2(aA, 0); loadW2(wA, 0);
        for (int k32 = 0; k32 < 8; k32 += 2) {
            loadA2(aB, k32 + 1); loadW2(wB, k32 + 1);
            #pragma unroll
            for (int mt = 0; mt < 2; mt++)
                #pragma unroll
                for (int nt = 0; nt < 4; nt++)
                    acc[mt][nt] = MFMA16(aA[mt], wA[nt], acc[mt][nt]);
            if (k32 + 2 < 8) { loadA2(aA, k32 + 2); loadW2(wA, k32 + 2); }
            #pragma unroll
            for (int mt = 0; mt < 2; mt++)
                #pragma unroll
                for (int nt = 0; nt < 4; nt++)
                    acc[mt][nt] = MFMA16(aB[mt], wB[nt], acc[mt][nt]);
        }
        #pragma unroll
        for (int mt = 0; mt < 2; mt++)
            #pragma unroll
            for (int nt = 0; nt < 4; nt++)
                #pragma unroll
                for (int rr = 0; rr < 4; rr++) {
                    int row = mt * 16 + quad * 4 + rr;
                    int col = col0 + nt * 16 + l15;
                    float v = acc[mt][nt][rr] + bg2[col];
                    float g = 1.f / (1.f + __expf(-v));
                    e32[mt][nt][rr] += g * b2f(cxb[row * GLDS + col]);
                }
        if (r < 2) {
            #pragma unroll
            for (int mt = 0; mt < 2; mt++)
                #pragma unroll
                for (int nt = 0; nt < 4; nt++)
                    #pragma unroll
                    for (int rr = 0; rr < 4; rr++) {
                        int row = mt * 16 + quad * 4 + rr;
                        int col = col0 + nt * 16 + l15;
                        ebf[row * GLDS + col] = f2b(e32[mt][nt][rr]);
                    }
        }
    }

    // final: write updated e (bf16 only; the f32 copy is dead downstream)
    #pragma unroll
    for (int mt = 0; mt < 2; mt++)
        #pragma unroll
        for (int nt = 0; nt < 4; nt++)
            #pragma unroll
            for (int rr = 0; rr < 4; rr++) {
                int row = r0 + mt * 16 + quad * 4 + rr;
                if (row < M)
                    xb[(size_t)row * HIDC + col0 + nt * 16 + l15] = f2b(e32[mt][nt][rr]);
            }
}

// ---------------- V transpose: [Mtok, stride VS] -> vtb [256][VTP] padded segments ----------
__global__ __launch_bounds__(256) void transpose_v(const bf16s* __restrict__ vsrc,
                                                   bf16s* __restrict__ vdst,
                                                   int Mtok, int Sk, int SkPad, int voff, int VS) {
    __shared__ bf16s t[64][72];
    int t0 = blockIdx.x * 64, d0 = blockIdx.y * 64;
    int tid = threadIdx.x;
    int lr = tid >> 2, lc = (tid & 3) * 16;
    if (t0 + lr < Mtok) {
        bf16x8 v0 = *(const bf16x8*)(vsrc + (size_t)(t0 + lr) * VS + d0 + lc);
        bf16x8 v1 = *(const bf16x8*)(vsrc + (size_t)(t0 + lr) * VS + d0 + lc + 8);
        *(bf16x8*)&t[lr][lc] = v0;
        *(bf16x8*)&t[lr][lc + 8] = v1;
    }
    __syncthreads();
    int dr = tid >> 2, tc = (tid & 3) * 16;
    #pragma unroll
    for (int u = 0; u < 16; u++) {
        int tok = t0 + tc + u;
        if (tok >= Mtok) break;
        int bidx = tok / Sk, s = tok - bidx * Sk;
        vdst[(size_t)(d0 + dr) * VTP + voff + bidx * SkPad + s] = t[tc + u][dr];
    }
}

// ---------------- flash v9: packed-K + 64 q-rows/wave + 4-way K-split ----------
__global__ __launch_bounds__(256) void flash8(const bf16s* __restrict__ qkv,
                                              const bf16s* __restrict__ vtb,
                                              const bf16s* __restrict__ ktb,
                                              bf16s* __restrict__ ctxall)
{
    __shared__ bf16s L[4][64 * 40];      // 20,480 B  P-tiles
    __shared__ float CMB[3][16][64];     // 12,288 B  combine (two passes: a0 then a1)
    __shared__ float CLS[3][4][64];      //  3,072 B  combine ls
    int bx = blockIdx.x;
    int sbg = bx >> 6, hb = bx & 63;
    int h = hb & 7, b = hb >> 3;
    int p = 0;
    while (sbg >= FP_SB0[p + 1]) p++;
    int wave = threadIdx.x >> 6, lane = threadIdx.x & 63;
    int l15 = lane & 15, quad = lane >> 4;
    int Sq = FP_SQ[p], Sk = FP_SK[p];
    bool ksp = (p < 3);
    int qrow0 = ksp ? (sbg - FP_SB0[p]) * 64
                    : ((sbg - FP_SB0[p]) * 4 + wave) * 64;
    if (qrow0 >= Sq) return;            // block-uniform when ksp (never taken there)
    int k0 = ksp ? wave * 784 : 0;
    int klim = ksp ? 784 : Sk;
    int qoff = FP_QOFF[p], koff = FP_KOFF[p];
    int voff = FP_VOFF[p], skp = FP_SKP[p];
    bf16s* ctxr = ctxall + (size_t)FP_R[p] * TTOK * HIDC;

    const bf16s* qrow = qkv + (size_t)(qoff + b * Sq) * QKVS + h * HDIM + quad * 8;
    bf16x8 qf[4];
    #pragma unroll
    for (int qi = 0; qi < 4; qi++)
        qf[qi] = *(const bf16x8*)(qrow + (size_t)min(qrow0 + qi * 16 + l15, Sq - 1) * QKVS);

    // packed K: wave's 16-row frag load = one contiguous 2KB block
    const bf16s* kp0 = ktb + ((size_t)h * TTOK + koff + b * Sk + k0 + l15) * 32 + quad * 8;
    const bf16s* kp16 = kp0 + 512;
    const bf16s* vp0 = vtb + (size_t)(h * HDIM + l15) * VTP + voff + b * skp + quad * 8;
    const bf16s* vp16 = vp0 + (size_t)16 * VTP;
    bf16s* Lw = L[wave];

    f32x4 a0[4], a1[4];   // a{dimhalf}[qi]
    float ls[4];
    #pragma unroll
    for (int qi = 0; qi < 4; qi++) { a0[qi] = ZERO4; a1[qi] = ZERO4; ls[qi] = 0.f; }
    int niter = (klim + 31) >> 5;

    bf16x8 kA0, kA1, vA0, vA1, kB0, kB1, vB0, vB1;

    auto loadKV = [&](bf16x8& kf0, bf16x8& kf1, bf16x8& vf0, bf16x8& vf1, int t) {
        size_t kb = (size_t)t << 10;
        kf0 = *(const bf16x8*)(kp0 + kb);
        kf1 = *(const bf16x8*)(kp16 + kb);
        vf0 = *(const bf16x8*)(vp0 + k0 + (t << 5));
        vf1 = *(const bf16x8*)(vp16 + k0 + (t << 5));
    };
    auto compute = [&](bf16x8 kf0, bf16x8 kf1, bf16x8 vf0, bf16x8 vf1, int t) {
        int kt = t << 5;
        f32x4 s0[4], s1[4];
        #pragma unroll
        for (int qi = 0; qi < 4; qi++) {
            s0[qi] = MFMA16(kf0, qf[qi], ZERO4);
            s1[qi] = MFMA16(kf1, qf[qi], ZERO4);
        }
        float p0[4][4], p1[4][4];
        #pragma unroll
        for (int qi = 0; qi < 4; qi++)
            #pragma unroll
            for (int r = 0; r < 4; r++) {
                p0[qi][r] = ex2(s0[qi][r]);
                p1[qi][r] = ex2(s1[qi][r]);
            }
        if (kt + 32 > klim) {  // tail: zero p for k >= klim (wave-uniform branch)
            int lim0 = klim - kt - quad * 4, lim1 = lim0 - 16;
            #pragma unroll
            for (int qi = 0; qi < 4; qi++)
                #pragma unroll
                for (int r = 0; r < 4; r++) {
                    if (r >= lim0) p0[qi][r] = 0.f;
                    if (r >= lim1) p1[qi][r] = 0.f;
                }
        }
        #pragma unroll
        for (int qi = 0; qi < 4; qi++) {
            #pragma unroll
            for (int r = 0; r < 4; r++) ls[qi] += p0[qi][r] + p1[qi][r];
            *(uint2*)&Lw[(qi * 16 + l15) * 40 + quad * 4] =
                make_uint2(cvtpk(p0[qi][0], p0[qi][1]), cvtpk(p0[qi][2], p0[qi][3]));
            *(uint2*)&Lw[(qi * 16 + l15) * 40 + 16 + quad * 4] =
                make_uint2(cvtpk(p1[qi][0], p1[qi][1]), cvtpk(p1[qi][2], p1[qi][3]));
        }
        #pragma unroll
        for (int qi = 0; qi < 4; qi++) {
            bf16x8 pb = *(const bf16x8*)&Lw[(qi * 16 + l15) * 40 + quad * 8];
            a0[qi] = MFMA16(vf0, pb, a0[qi]);
            a1[qi] = MFMA16(vf1, pb, a1[qi]);
        }
    };

    loadKV(kA0, kA1, vA0, vA1, 0);
    for (int t = 0; t < niter; t += 2) {
        if (t + 1 < niter) loadKV(kB0, kB1, vB0, vB1, t + 1);
        compute(kA0, kA1, vA0, vA1, t);
        if (t + 2 < niter) loadKV(kA0, kA1, vA0, vA1, t + 2);
        if (t + 1 < niter) compute(kB0, kB1, vB0, vB1, t + 1);
    }

    if (ksp) {
        // two-pass LDS combine across the 4 k-chunk waves (keeps LDS <= 36 KB)
        if (wave > 0) {
            #pragma unroll
            for (int qi = 0; qi < 4; qi++) {
                #pragma unroll
                for (int r = 0; r < 4; r++) CMB[wave - 1][qi * 4 + r][lane] = a0[qi][r];
                CLS[wave - 1][qi][lane] = ls[qi];
            }
        }
        __syncthreads();
        if (wave == 0) {
            #pragma unroll
            for (int w = 0; w < 3; w++)
                #pragma unroll
                for (int qi = 0; qi < 4; qi++) {
                    #pragma unroll
                    for (int r = 0; r < 4; r++) a0[qi][r] += CMB[w][qi * 4 + r][lane];
                    ls[qi] += CLS[w][qi][lane];
                }
        }
        __syncthreads();
        if (wave > 0) {
            #pragma unroll
            for (int qi = 0; qi < 4; qi++)
                #pragma unroll
                for (int r = 0; r < 4; r++) CMB[wave - 1][qi * 4 + r][lane] = a1[qi][r];
        }
        __syncthreads();
        if (wave > 0) return;
        #pragma unroll
        for (int w = 0; w < 3; w++)
            #pragma unroll
            for (int qi = 0; qi < 4; qi++)
                #pragma unroll
                for (int r = 0; r < 4; r++) a1[qi][r] += CMB[w][qi * 4 + r][lane];
    }

    #pragma unroll
    for (int qi = 0; qi < 4; qi++) {
        float l = ls[qi];
        l += __shfl_xor(l, 16); l += __shfl_xor(l, 32);
        float inv = 1.f / l;
        if (qrow0 + qi * 16 + l15 < Sq) {
            size_t o = (size_t)(qoff + b * Sq + qrow0 + qi * 16 + l15) * HIDC + h * HDIM;
            *(uint2*)(ctxr + o + quad * 4) =
                make_uint2(cvtpk(a0[qi][0] * inv, a0[qi][1] * inv),
                           cvtpk(a0[qi][2] * inv, a0[qi][3] * inv));
            *(uint2*)(ctxr + o + 16 + quad * 4) =
                make_uint2(cvtpk(a1[qi][0] * inv, a1[qi][1] * inv),
                           cvtpk(a1[qi][2] * inv, a1[qi][3] * inv));
        }
    }
}

// ---------------- CECM: pooled mean partials over all scales ----------------
__global__ __launch_bounds__(256) void pool2(const bf16s* __restrict__ xb,
                                             float* __restrict__ partial) {
    int chunk = blockIdx.x, b = blockIdx.y, i = blockIdx.z;
    int c = threadIdx.x;
    int S = DC_S[i];
    int len = (S + 31) / 32;
    int s0 = chunk * len, s1 = min(S, s0 + len);
    float acc = 0.f;
    const bf16s* base = xb + (size_t)(DC_BOFF[i] + b * S) * HIDC + c;
    for (int s = s0; s < s1; s++) acc += b2f(base[(size_t)s * HIDC]);
    partial[(size_t)((i * NB + b) * 32 + chunk) * HIDC + c] = acc;
}

// ---------------- CECM: kernel generator MLP (all scales) ----------------
__global__ __launch_bounds__(256) void kgen2(
    const float* __restrict__ partial,
    const float* __restrict__ Wcp, const float* __restrict__ bcp,
    const float* __restrict__ Wkg1, const float* __restrict__ bkg1,
    const float* __restrict__ Wkg2, const float* __restrict__ bkg2,
    float* __restrict__ kern)
{
    __shared__ float pl[256], cv[256], h1[512];
    int b = blockIdx.x, i = blockIdx.y, t = threadIdx.x;
    float invS = 1.f / (float)DC_S[i];
    const float* pb = partial + (size_t)((i * NB + b) * 32) * HIDC;
    float s = 0.f;
    for (int jc = 0; jc < 32; jc++) s += pb[(size_t)jc * HIDC + t];
    pl[t] = s * invS;
    __syncthreads();
    float a = bcp[t];
    for (int k = 0; k < 256; k++) a += Wcp[t * 256 + k] * pl[k];
    cv[t] = fmaxf(a, 0.f);
    __syncthreads();
    for (int r = t; r < 512; r += 256) {
        float a2 = bkg1[r];
        for (int k = 0; k < 256; k++) a2 += Wkg1[r * 256 + k] * cv[k];
        h1[r] = fmaxf(a2, 0.f);
    }
    __syncthreads();
    if (t < 72) {
        float a3 = bkg2[t];
        for (int k = 0; k < 512; k++) a3 += Wkg2[t * 512 + k] * h1[k];
        kern[(i * NB + b) * 72 + t] = a3;
    }
}

// ---------------- CECM: fused dynamic depthwise 3x3 over all scales ----------------
__global__ __launch_bounds__(256) void dwconv2(const bf16s* __restrict__ xtb,
                                               const float* __restrict__ kern,
                                               bf16s* __restrict__ y) {
    int tok = blockIdx.x;
    int i = (tok >= DC_BOFF[1]) + (tok >= DC_BOFF[2]) + (tok >= DC_BOFF[3]);
    int S = DC_S[i], W = DC_HW[i];
    int local = tok - DC_BOFF[i];
    int b = local / S, s = local - b * S;
    int hh = s / W, ww = s - hh * W;
    int c = threadIdx.x;
    const float* kb = kern + (i * NB + b) * 72 + (c >> 5) * 9;
    const bf16s* xbase = xtb + (size_t)(DC_BOFF[i] + b * S) * HIDC + c;
    float acc = 0.f;
    #pragma unroll
    for (int ky = 0; ky < 3; ky++) {
        int hy = hh + ky - 1;
        if (hy < 0 || hy >= W) continue;
        #pragma unroll
        for (int kx = 0; kx < 3; kx++) {
            int wx = ww + kx - 1;
            if (wx < 0 || wx >= W) continue;
            acc += kb[ky * 3 + kx] * b2f(xbase[(size_t)(hy * W + wx) * HIDC]);
        }
    }
    y[(size_t)tok * HIDC + c] = f2b(acc);
}

// ---------------- BN stats v2: 512 blocks, float4 loads, LDS row-group reduce ----------
__global__ __launch_bounds__(256) void bn1(const float* __restrict__ yo,
                                           float* __restrict__ bnp) {
    __shared__ float red[4][64][8];
    int chunk = blockIdx.x, i = blockIdx.y, t = threadIdx.x;
    int rg = t >> 6, cq = (t & 63) * 4;
    int Nrows = NB * DC_S[i];
    const float* base = yo + (size_t)DC_BOFF[i] * HIDC + cq;
    f32x4 s = ZERO4, ss = ZERO4;
    for (int r = chunk * 4 + rg; r < Nrows; r += BN1_CH * 4) {
        f32x4 v = *(const f32x4*)(base + (size_t)r * HIDC);
        s += v; ss += v * v;
    }
    #pragma unroll
    for (int j = 0; j < 4; j++) { red[rg][t & 63][j] = s[j]; red[rg][t & 63][4 + j] = ss[j]; }
    __syncthreads();
    if (t < 64) {
        #pragma unroll
        for (int j = 0; j < 4; j++) {
            float a = red[0][t][j] + red[1][t][j] + red[2][t][j] + red[3][t][j];
            float b = red[0][t][4 + j] + red[1][t][4 + j] + red[2][t][4 + j] + red[3][t][4 + j];
            bnp[(size_t)(i * BN1_CH + chunk) * 512 + t * 4 + j] = a;
            bnp[(size_t)(i * BN1_CH + chunk) * 512 + 256 + t * 4 + j] = b;
        }
    }
}
__global__ __launch_bounds__(256) void bn2(const float* __restrict__ bnp,
                                           float* __restrict__ stat) {
    int i = blockIdx.x, c = threadIdx.x;
    float s = 0.f, ss = 0.f;
    for (int ch = 0; ch < BN1_CH; ch++) {
        s += bnp[(size_t)(i * BN1_CH + ch) * 512 + c];
        ss += bnp[(size_t)(i * BN1_CH + ch) * 512 + 256 + c];
    }
    float inv = 1.f / (float)(NB * DC_S[i]);
    float mu = s * inv;
    float var = fmaxf(ss * inv - mu * mu, 0.f);
    stat[i * 512 + c] = mu;
    stat[i * 512 + 256 + c] = rsqrtf(var + 1e-5f);
}

// ---------------- fused final output (tiled transpose), all scales ----------------
__global__ __launch_bounds__(256) void final2(const bf16s* __restrict__ xtb,
                                              const float* __restrict__ yo,
                                              const float* __restrict__ stat,
                                              const float* __restrict__ gamma,
                                              const float* __restrict__ beta,
                                              float* __restrict__ out) {
    __shared__ float tile[64][65];
    int bx = blockIdx.x;
    int i = (bx >= DC_FOS[1]) + (bx >= DC_FOS[2]) + (bx >= DC_FOS[3]);
    int S = DC_S[i];
    int s0 = (bx - DC_FOS[i]) * 64;
    int cstrip = blockIdx.y, b = blockIdx.z;
    int g = threadIdx.x >> 6, sl = threadIdx.x & 63;
    {
        int c = cstrip * 64 + sl;
        float mu = stat[i * 512 + c], rstd = stat[i * 512 + 256 + c];
        float ga = gamma[c], be = beta[c];
        size_t rbase = (size_t)(DC_BOFF[i] + b * S) * HIDC + c;
        #pragma unroll
        for (int u = 0; u < 16; u++) {
            int s = s0 + g * 16 + u;
            if (s < S) {
                size_t r = rbase + (size_t)s * HIDC;
                tile[g * 16 + u][sl] = b2f(xtb[r]) + (yo[r] - mu) * rstd * ga + be;
            }
        }
    }
    __syncthreads();
    {
        int s = s0 + sl;
        if (s < S) {
            #pragma unroll
            for (int cs = 0; cs < 16; cs++) {
                int cl = g * 16 + cs;
                out[((size_t)(b * HIDC + cstrip * 64 + cl)) * STOT + DC_GOFF[i] + s] = tile[sl][cl];
            }
        }
    }
}

// ---------------- host helpers ----------------
static inline void gemm_launch(hipStream_t st, const bf16s* A, const bf16s* A2,
                               const bf16s* W, const float* bias,
                               float* Cf, bf16s* Cb, const bf16s* Gaux,
                               int M, int N, int K, int K1, int epi) {
    dim3 grid(N / 128, (M + 63) / 64), blk(256);
    switch (epi) {
        case 0: gemm3<0><<<grid, blk, 0, st>>>(A, A2, W, bias, Cf, Cb, Gaux, M, N, K, K1); break;
        case 1: gemm3<1><<<grid, blk, 0, st>>>(A, A2, W, bias, Cf, Cb, Gaux, M, N, K, K1); break;
        default: gemm3<4><<<grid, blk, 0, st>>>(A, A2, W, bias, Cf, Cb, Gaux, M, N, K, K1); break;
    }
}

extern "C" void kernel_launch(void* const* d_in, const int* in_sizes, int n_in,
                              void* d_out, int out_size, void* d_ws, size_t ws_size,
                              hipStream_t stream) {
    typedef const float* fp;
    fp f[4]  = {(fp)d_in[0], (fp)d_in[3], (fp)d_in[6], (fp)d_in[9]};
    fp Wp[4] = {(fp)d_in[1], (fp)d_in[4], (fp)d_in[7], (fp)d_in[10]};
    fp bp[4] = {(fp)d_in[2], (fp)d_in[5], (fp)d_in[8], (fp)d_in[11]};
    fp Wq = (fp)d_in[12], Wk = (fp)d_in[13], Wv = (fp)d_in[14], Wo = (fp)d_in[15];
    fp Wg1 = (fp)d_in[16], Wg2 = (fp)d_in[17], Wcp = (fp)d_in[18];
    fp Wkg1 = (fp)d_in[19], Wkg2 = (fp)d_in[20], Wit = (fp)d_in[21], Wot = (fp)d_in[22];
    fp bq = (fp)d_in[23], bk = (fp)d_in[24], bv = (fp)d_in[25], bo = (fp)d_in[26];
    fp bg1 = (fp)d_in[27], bg2 = (fp)d_in[28], bcp = (fp)d_in[29];
    fp bkg1 = (fp)d_in[30], bkg2 = (fp)d_in[31], bit = (fp)d_in[32], bot = (fp)d_in[33];
    fp gamma = (fp)d_in[34], beta = (fp)d_in[35];
    float* out = (float*)d_out;

    const size_t NT = (size_t)TTOK * HIDC;   // 8,529,920

    // ---- workspace carve ----
    float* x     = (float*)d_ws;               // e f32; phase 4: yo aliases x
    bf16s* xb    = (bf16s*)(x + NT);           // e bf16 mirror
    bf16s* qkvb  = xb + NT;                    // [TTOK, 768]; dead after flash -> ctxob2
    bf16s* vtb   = qkvb + (size_t)TTOK * QKVS; // [256][VTP] (zero-filled)
    bf16s* ctxall= vtb + (size_t)HIDC * VTP;   // 3 x [TTOK,256] flash ctx
    bf16s* ctxob = ctxall + 3 * NT;            // repurposed: ktb (packed K)
    float* partial = (float*)(ctxob + 3 * NT);
    float* kern    = partial + 4 * NB * 32 * HIDC;
    float* bnp     = kern + 4 * NB * 72;
    float* bnstat  = bnp + 4 * 32 * 512;
    float* bqkv    = bnstat + 4 * 512;         // 768
    bf16s* wseg    = (bf16s*)(bqkv + 768);
    // aliases
    bf16s* atmp = ctxall;                      // phase-1 scratch
    bf16s* hb   = ctxall;                      // dwconv out (phase 4; ctxall dead then)
    bf16s* xtb  = ctxall + NT;                 // Wit out (phase 4)
    float* yo   = x;                           // phase-4 Wot out (e f32 dead)
    float* bnp2 = partial;                     // bn1 partials reuse `partial`
    bf16s* ktb  = ctxob;                       // packed K [8][TTOK][32]
    bf16s* ctxob2 = qkvb;                      // Wo out: qkvb region (3NT exact), dead after flash

    // weight pointers in wseg (all bf16 weights stored SWIZZLED)
    bf16s* wpb[4]; size_t wo_ = 0;
    for (int i = 0; i < 4; i++) { wpb[i] = wseg + wo_; wo_ += (size_t)HIDC * D_IN[i]; }
    bf16s* wqkvb = wseg + wo_; wo_ += (size_t)QKVS * 256;
    bf16s* wob  = wseg + wo_; wo_ += 65536;
    bf16s* wg1b = wseg + wo_; wo_ += 131072;
    bf16s* wg2b = wseg + wo_; wo_ += 65536;
    bf16s* witb = wseg + wo_; wo_ += 65536;
    bf16s* wotb = wseg + wo_; wo_ += 65536;

    // ---- fused weight conversion + swizzle (Wq/bq pre-scaled by 1/sqrt(32)*log2e) ----
    {
        CvtArgs ca;
        const float* srcs[15] = {Wp[0], Wp[1], Wp[2], Wp[3], Wq, Wk, Wv, Wo, Wg1, Wg2,
                                 Wit, Wot, bq, bk, bv};
        void* dsts[15] = {wpb[0], wpb[1], wpb[2], wpb[3], wqkvb, wqkvb + 65536,
                          wqkvb + 131072, wob, wg1b, wg2b, witb, wotb,
                          bqkv, bqkv + 256, bqkv + 512};
        int ns[15] = {16384, 32768, 65536, 131072, 65536, 65536, 65536, 65536, 131072,
                      65536, 65536, 65536, 256, 256, 256};
        int modes[15] = {0, 0, 0, 0, 1, 0, 0, 0, 0, 0, 0, 0, 3, 2, 2};
        int Ks[15] = {64, 128, 256, 512, 256, 256, 256, 256, 512, 256, 256, 256, 0, 0, 0};
        int total = 0;
        for (int k = 0; k < 15; k++) { ca.src[k] = srcs[k]; ca.dst[k] = dsts[k];
                                       ca.n[k] = ns[k]; ca.mode[k] = modes[k];
                                       ca.K[k] = Ks[k]; total += ns[k]; }
        cvt_all<<<dim3((total + 255) / 256), dim3(256), 0, stream>>>(ca, total);
    }
    // zero vtb so pad regions / unguarded tail reads are finite
    hipMemsetAsync(vtb, 0, (size_t)HIDC * VTP * sizeof(bf16s), stream);

    // ---- phase 1: per-scale 1x1 projection -> x (f32) + xb (bf16) ----
    for (int i = 0; i < 4; i++) {
        int S = S_SZ[i], D = D_IN[i], M = NB * S;
        transpose_f2<<<dim3((S + 31) / 32, D / 32, NB), dim3(256), 0, stream>>>(f[i], atmp, D, S);
        gemm_launch(stream, atmp, nullptr, wpb[i], bp[i],
                    x + (size_t)BOFF[i] * HIDC, xb + (size_t)BOFF[i] * HIDC, nullptr,
                    M, HIDC, D, D, 1);
    }

    // ---- phase 2: merged QKV GEMM + V transpose + K pack ----
    gemm_launch(stream, xb, nullptr, wqkvb, bqkv, nullptr, qkvb, nullptr, TTOK, QKVS, 256, 256, 0);
    for (int j = 0; j < 4; j++) {
        int Mtok = NB * S_SZ[j];
        transpose_v<<<dim3((Mtok + 63) / 64, 4), dim3(256), 0, stream>>>(
            qkvb + 512 + (size_t)BOFF[j] * QKVS, vtb, Mtok, S_SZ[j], SKPAD_H[j], VWOFF_H[j], QKVS);
    }
    kpack<<<dim3((TTOK + 7) / 8), dim3(256), 0, stream>>>(qkvb + 256, ktb);

    // ---- phase 3: flash, batched Wo (out -> dead qkvb region), fused gate chain ----
    flash8<<<dim3(69 * 64), dim3(256), 0, stream>>>(qkvb, vtb, ktb, ctxall);
    gemm_launch(stream, ctxall, nullptr, wob, bo, nullptr, ctxob2, nullptr, 3 * TTOK, HIDC, 256, 256, 0);
    gatefuse<<<dim3((TTOK + 31) / 32), dim3(256), 0, stream>>>(
        ctxob2, xb, x, wg1b, bg1, wg2b, bg2, TTOK);

    // ---- phase 4: CECM fused across scales ----
    pool2<<<dim3(32, NB, 4), dim3(256), 0, stream>>>(xb, partial);
    kgen2<<<dim3(NB, 4), dim3(256), 0, stream>>>(partial, Wcp, bcp, Wkg1, bkg1, Wkg2, bkg2, kern);
    gemm_launch(stream, xb, nullptr, witb, bit, nullptr, xtb, nullptr, TTOK, HIDC, 256, 256, 0);
    dwconv2<<<dim3(TTOK), dim3(256), 0, stream>>>(xtb, kern, hb);
    gemm_launch(stream, hb, nullptr, wotb, bot, yo, nullptr, nullptr, TTOK, HIDC, 256, 256, 4);
    bn1<<<dim3(BN1_CH, 4), dim3(256), 0, stream>>>(yo, bnp2);
    bn2<<<dim3(4), dim3(256), 0, stream>>>(bnp2, bnstat);
    final2<<<dim3(67, 4, NB), dim3(256), 0, stream>>>(xtb, yo, bnstat, gamma, beta, out);
}

// Round 15
// 822.338 us; speedup vs baseline: 1.3426x; 1.0297x over previous
//
#include <hip/hip_runtime.h>
#include <hip/hip_bf16.h>
#include <cstddef>

// ---------------- constants ----------------
#define NB 8
#define HIDC 256
#define NHEAD 8
#define HDIM 32
#define TTOK 33320
#define STOT 4165
#define VTP 33440
#define QKVS 768          // merged qkv row stride
// 1/sqrt(32) * log2(e): fold softmax scale AND exp->exp2 conversion into Wq/bq
#define QSC2 0.2550348757f
#define BN1_CH 128        // bn1 chunks per scale (512 blocks total)

static const int H_SZ[4]   = {56, 28, 14, 7};
static const int S_SZ[4]   = {3136, 784, 196, 49};
static const int D_IN[4]   = {64, 128, 256, 512};
static const int BOFF[4]   = {0, 25088, 31360, 32928};

__constant__ int DC_S[4]     = {3136, 784, 196, 49};
__constant__ int DC_HW[4]    = {56, 28, 14, 7};
__constant__ int DC_BOFF[4]  = {0, 25088, 31360, 32928};
__constant__ int DC_GOFF[4]  = {0, 3136, 3920, 4116};
__constant__ int DC_FOS[4]   = {0, 49, 62, 66};   // final_out 64-token block starts (total 67)
__constant__ int DC_SKPAD[4] = {3136, 784, 200, 56};
__constant__ int DC_VWOFF[4] = {0, 25088, 31360, 32960};

// flash pair tables, sorted by Sk desc (long waves dispatch first).
// Pairs 0-2 (Sk=3136): K-SPLIT blocks = 64 q rows, 4 waves x 784-key chunks, LDS combine;
//   nblk = ceil(Sq/64).
// Pairs 3-11: block = 4 independent waves x 64 q rows; nblk = ceil(Sq/256).
__constant__ int FP_SQ[12]   = {784,196,49,3136,196,49,3136,784,49,3136,784,196};
__constant__ int FP_SK[12]   = {3136,3136,3136,784,784,784,196,196,196,49,49,49};
__constant__ int FP_QOFF[12] = {25088,31360,32928,0,31360,32928,0,25088,32928,0,25088,31360};
__constant__ int FP_KOFF[12] = {0,0,0,25088,25088,25088,31360,31360,31360,32928,32928,32928};
__constant__ int FP_VOFF[12] = {0,0,0,25088,25088,25088,31360,31360,31360,32960,32960,32960};
__constant__ int FP_SKP[12]  = {3136,3136,3136,784,784,784,200,200,200,56,56,56};
__constant__ int FP_R[12]    = {0,0,0,0,1,1,1,1,2,2,2,2};
__constant__ int FP_SB0[13]  = {0,13,17,18,31,32,33,46,50,51,64,68,69};

typedef short bf16s;
typedef bf16s bf16x8 __attribute__((ext_vector_type(8)));
typedef float f32x4 __attribute__((ext_vector_type(4)));

// fast f32->bf16 (round half up; |err| == RNE ulp bound, no NaN/inf in data)
static __device__ inline bf16s f2b(float f) {
    return (bf16s)((__float_as_uint(f) + 0x8000u) >> 16);
}
static __device__ inline float b2f(bf16s s) {
    return __uint_as_float(((unsigned)(unsigned short)s) << 16);
}
// pack two f32 -> two bf16 in one dword (single HW instr, RNE; a in low half)
static __device__ inline unsigned cvtpk(float a, float b) {
    unsigned r;
    asm("v_cvt_pk_bf16_f32 %0, %1, %2" : "=v"(r) : "v"(a), "v"(b));
    return r;
}
static __device__ inline float ex2(float x) {
#if __has_builtin(__builtin_amdgcn_exp2f)
    return __builtin_amdgcn_exp2f(x);
#else
    return exp2f(x);
#endif
}
#define MFMA16(a, b, c) __builtin_amdgcn_mfma_f32_16x16x32_bf16(a, b, c, 0, 0, 0)
#define ZERO4 ((f32x4){0.f, 0.f, 0.f, 0.f})

// ---------------- fused weight conversion + W swizzle ----------------
// Swizzled weight layout for gemm3: for (n,k) with n-block c64=n>>6, k-block k32=k>>5:
//   dst = ((c64*(K/32) + k32)*4 + nt)*512 + l15*32 + q*8 + j
// where nt=(n>>4)&3, l15=n&15, q=(k>>3)&3, j=k&7.  One wave W-frag load = 1KB contiguous.
struct CvtArgs {
    const float* src[15];
    void* dst[15];
    int n[15];
    int mode[15];   // 0: bf16 swizzled  1: bf16 swizzled *QSC2  2: f32 copy  3: f32*QSC2
    int K[15];      // weight K (pow2) for swizzle modes
};
__global__ __launch_bounds__(256) void cvt_all(CvtArgs a, int total) {
    int idx = blockIdx.x * 256 + threadIdx.x;
    if (idx >= total) return;
    int seg = 0, off = idx;
    while (off >= a.n[seg]) { off -= a.n[seg]; seg++; }
    float v = a.src[seg][off];
    int m = a.mode[seg];
    if (m == 1 || m == 3) v *= QSC2;
    if (m <= 1) {
        int K = a.K[seg];
        int kz = __builtin_ctz(K);
        int n = off >> kz, k = off & (K - 1);
        int c64 = n >> 6, nt = (n >> 4) & 3, l15 = n & 15;
        int k32 = k >> 5, q = (k >> 3) & 3, j = k & 7;
        int dst = (((c64 * (K >> 5) + k32) * 4 + nt) << 9) + l15 * 32 + q * 8 + j;
        ((bf16s*)a.dst[seg])[dst] = f2b(v);
    } else {
        ((float*)a.dst[seg])[off] = v;
    }
}

// ---------------- tiled transpose f [B,D,S] f32 -> A [B*S, D] bf16 ----------------
__global__ __launch_bounds__(256) void transpose_f2(const float* __restrict__ f,
                                                    bf16s* __restrict__ A, int D, int S) {
    __shared__ float t[32][33];
    int s0 = blockIdx.x * 32, d0 = blockIdx.y * 32, b = blockIdx.z;
    int sl = threadIdx.x & 31, dl = threadIdx.x >> 5;
    #pragma unroll
    for (int dd = 0; dd < 32; dd += 8) {
        int s = s0 + sl;
        t[dl + dd][sl] = (s < S) ? f[((size_t)(b * D + d0 + dl + dd)) * S + s] : 0.f;
    }
    __syncthreads();
    int dc = threadIdx.x & 31, sg = threadIdx.x >> 5;
    #pragma unroll
    for (int ss = 0; ss < 32; ss += 8) {
        int s = s0 + sg + ss;
        if (s < S) A[((size_t)(b * S + s)) * D + d0 + dc] = f2b(t[dc][sg + ss]);
    }
}

// ---------------- MFMA GEMM v4: 64x128 block tile ----------------
// block 256 = 4 waves (2 row-groups x 2 col-groups); wave tile 32x64; block tile 64x128.
// EPI 0: bf16->Cb | 1: f32->Cf + bf16->Cb | 4: f32->Cf
// EPI 5: QKV scatter — Q cols -> Cb (qkvb), K cols -> ktb (via Cf), V cols -> vtb (via Gaux).
//        Section branches are wave-uniform (sections align to 64-col wave tiles).
template <int EPI>
__global__ __launch_bounds__(256) void gemm3(
    const bf16s* __restrict__ A, const bf16s* __restrict__ A2,
    const bf16s* __restrict__ W, const float* __restrict__ bias,
    float* __restrict__ Cf, bf16s* __restrict__ Cb, const bf16s* __restrict__ Gaux,
    int M, int N, int K, int K1)
{
    int tid = threadIdx.x, lane = tid & 63, wave = tid >> 6;
    int l15 = lane & 15, quad = lane >> 4;
    int row0 = blockIdx.y * 64 + (wave >> 1) * 32;
    int col0 = blockIdx.x * 128 + (wave & 1) * 64;
    int K2 = K - K1;
    int nk = K >> 5;
    int c64 = (blockIdx.x << 1) + (wave & 1);
    const bf16s* wbase = W + (size_t)c64 * ((size_t)nk << 11) + l15 * 32 + quad * 8;
    int ra[2];
    #pragma unroll
    for (int mt = 0; mt < 2; mt++) ra[mt] = min(row0 + mt * 16 + l15, M - 1);

    f32x4 acc[2][4];
    #pragma unroll
    for (int i = 0; i < 2; i++)
        #pragma unroll
        for (int j = 0; j < 4; j++) acc[i][j] = ZERO4;

    bf16x8 aA[2], wA[4], aB[2], wB[4];

    auto loadA = [&](bf16x8* af, int k32) {
        int kk = (k32 << 5) + quad * 8;
        if (kk < K1) {
            #pragma unroll
            for (int mt = 0; mt < 2; mt++)
                af[mt] = *(const bf16x8*)(A + (size_t)ra[mt] * K1 + kk);
        } else {
            int k2 = kk - K1;
            #pragma unroll
            for (int mt = 0; mt < 2; mt++)
                af[mt] = *(const bf16x8*)(A2 + (size_t)ra[mt] * K2 + k2);
        }
    };
    auto loadW = [&](bf16x8* wf, int k32) {
        const bf16s* p = wbase + ((size_t)k32 << 11);
        #pragma unroll
        for (int nt = 0; nt < 4; nt++)
            wf[nt] = *(const bf16x8*)(p + nt * 512);
    };

    loadA(aA, 0); loadW(wA, 0);
    for (int k32 = 0; k32 < nk; k32 += 2) {
        loadA(aB, k32 + 1); loadW(wB, k32 + 1);
        #pragma unroll
        for (int mt = 0; mt < 2; mt++)
            #pragma unroll
            for (int nt = 0; nt < 4; nt++)
                acc[mt][nt] = MFMA16(aA[mt], wA[nt], acc[mt][nt]);
        if (k32 + 2 < nk) { loadA(aA, k32 + 2); loadW(wA, k32 + 2); }
        #pragma unroll
        for (int mt = 0; mt < 2; mt++)
            #pragma unroll
            for (int nt = 0; nt < 4; nt++)
                acc[mt][nt] = MFMA16(aB[mt], wB[nt], acc[mt][nt]);
    }

    #pragma unroll
    for (int mt = 0; mt < 2; mt++) {
        int rowb = row0 + mt * 16 + quad * 4;
        #pragma unroll
        for (int nt = 0; nt < 4; nt++) {
            int col = col0 + nt * 16 + l15;
            float bv = bias ? bias[col] : 0.f;
            #pragma unroll
            for (int r = 0; r < 4; r++) {
                int row = rowb + r;
                if (row >= M) continue;
                size_t off = (size_t)row * N + col;
                float v = acc[mt][nt][r] + bv;
                if (EPI == 0) {
                    Cb[off] = f2b(v);
                } else if (EPI == 1) {
                    Cf[off] = v; Cb[off] = f2b(v);
                } else if (EPI == 5) {
                    if (col < 256) {
                        Cb[off] = f2b(v);                    // Q -> qkvb
                    } else if (col < 512) {
                        bf16s* ktb_ = (bf16s*)Cf;            // K -> packed ktb[h][tok][32]
                        ktb_[((size_t)((col - 256) >> 5) * TTOK + row) * 32 + (col & 31)] = f2b(v);
                    } else {
                        bf16s* vtb_ = (bf16s*)Gaux;          // V -> transposed vtb[d][...]
                        int d = col - 512;
                        int i3 = (row >= DC_BOFF[1]) + (row >= DC_BOFF[2]) + (row >= DC_BOFF[3]);
                        int local = row - DC_BOFF[i3];
                        int S = DC_S[i3];
                        int bb = local / S, s = local - bb * S;
                        vtb_[(size_t)d * VTP + DC_VWOFF[i3] + bb * DC_SKPAD[i3] + s] = f2b(v);
                    }
                } else {
                    Cf[off] = v;
                }
            }
        }
    }
}

// ---------------- fused gate chain v1: 3 rounds of Wg1/Wg2/update (2-stage MFMA) --------
// Per block: 32 rows of e held in f32 REGISTERS (each wave owns a 64-col slice) + bf16
// mirrors of e/ctx/h in LDS (stride 264 kills bank conflicts). Weights read swizzled
// from L2. NOTE: uncapped launch bounds — (256,3) made the allocator pin 84 VGPRs and
// spill ~1GB (r13); 3-stage Wo fusion hit the 256-VGPR cap and spilled (r11). This
// 2-stage / uncapped config is the verified optimum (152us).
#define GLDS 264
__global__ __launch_bounds__(256) void gatefuse(
    const bf16s* __restrict__ ctxob, bf16s* __restrict__ xb, const float* __restrict__ x,
    const bf16s* __restrict__ Wg1, const float* __restrict__ bg1,
    const bf16s* __restrict__ Wg2, const float* __restrict__ bg2, int M)
{
    __shared__ bf16s ebf[32 * GLDS], cxb[32 * GLDS], hbf[32 * GLDS];
    int tid = threadIdx.x, lane = tid & 63, wave = tid >> 6;
    int l15 = lane & 15, quad = lane >> 4;
    int r0 = blockIdx.x * 32;
    int col0 = wave * 64;

    // init: ebf (bf16 mirror) from xb; e32 (f32, reg) from x
    #pragma unroll
    for (int u = 0; u < 4; u++) {
        int idx = u * 256 + tid;
        int row = idx >> 5, ch = (idx & 31) * 8;
        *(bf16x8*)&ebf[row * GLDS + ch] =
            *(const bf16x8*)(xb + (size_t)min(r0 + row, M - 1) * HIDC + ch);
    }
    f32x4 e32[2][4];
    #pragma unroll
    for (int mt = 0; mt < 2; mt++)
        #pragma unroll
        for (int nt = 0; nt < 4; nt++)
            #pragma unroll
            for (int rr = 0; rr < 4; rr++) {
                int row = min(r0 + mt * 16 + quad * 4 + rr, M - 1);
                e32[mt][nt][rr] = x[(size_t)row * HIDC + col0 + nt * 16 + l15];
            }

    const bf16s* w1base = Wg1 + ((size_t)wave << 15) + l15 * 32 + quad * 8;  // nk=16
    const bf16s* w2base = Wg2 + ((size_t)wave << 14) + l15 * 32 + quad * 8;  // nk=8

    for (int r = 0; r < 3; r++) {
        __syncthreads();   // prev round's cxb reads + ebf writes complete
        const bf16s* crp = ctxob + (size_t)r * ((size_t)TTOK * HIDC);
        #pragma unroll
        for (int u = 0; u < 4; u++) {
            int idx = u * 256 + tid;
            int row = idx >> 5, ch = (idx & 31) * 8;
            *(bf16x8*)&cxb[row * GLDS + ch] =
                *(const bf16x8*)(crp + (size_t)min(r0 + row, M - 1) * HIDC + ch);
        }
        __syncthreads();

        f32x4 acc[2][4];
        bf16x8 aA[2], wA[4], aB[2], wB[4];

        // ---- Wg1: K=512 = [e(256) ++ ctx(256)], output h (relu, bf16 -> hbf) ----
        #pragma unroll
        for (int i = 0; i < 2; i++)
            #pragma unroll
            for (int j = 0; j < 4; j++) acc[i][j] = ZERO4;
        auto loadA1 = [&](bf16x8* af, int k32) {
            int kk = (k32 << 5) + quad * 8;
            if (kk < 256) {
                #pragma unroll
                for (int mt = 0; mt < 2; mt++)
                    af[mt] = *(const bf16x8*)&ebf[(mt * 16 + l15) * GLDS + kk];
            } else {
                #pragma unroll
                for (int mt = 0; mt < 2; mt++)
                    af[mt] = *(const bf16x8*)&cxb[(mt * 16 + l15) * GLDS + kk - 256];
            }
        };
        auto loadW1 = [&](bf16x8* wf, int k32) {
            const bf16s* p = w1base + ((size_t)k32 << 11);
            #pragma unroll
            for (int nt = 0; nt < 4; nt++)
                wf[nt] = *(const bf16x8*)(p + nt * 512);
        };
        loadA1(aA, 0); loadW1(wA, 0);
        for (int k32 = 0; k32 < 16; k32 += 2) {
            loadA1(aB, k32 + 1); loadW1(wB, k32 + 1);
            #pragma unroll
            for (int mt = 0; mt < 2; mt++)
                #pragma unroll
                for (int nt = 0; nt < 4; nt++)
                    acc[mt][nt] = MFMA16(aA[mt], wA[nt], acc[mt][nt]);
            if (k32 + 2 < 16) { loadA1(aA, k32 + 2); loadW1(wA, k32 + 2); }
            #pragma unroll
            for (int mt = 0; mt < 2; mt++)
                #pragma unroll
                for (int nt = 0; nt < 4; nt++)
                    acc[mt][nt] = MFMA16(aB[mt], wB[nt], acc[mt][nt]);
        }
        #pragma unroll
        for (int mt = 0; mt < 2; mt++)
            #pragma unroll
            for (int nt = 0; nt < 4; nt++)
                #pragma unroll
                for (int rr = 0; rr < 4; rr++) {
                    int row = mt * 16 + quad * 4 + rr;
                    int col = col0 + nt * 16 + l15;
                    hbf[row * GLDS + col] = f2b(fmaxf(acc[mt][nt][rr] + bg1[col], 0.f));
                }
        __syncthreads();   // hbf visible

        // ---- Wg2: K=256 from hbf; then e += sig(v) * ctx ----
        #pragma unroll
        for (int i = 0; i < 2; i++)
            #pragma unroll
            for (int j = 0; j < 4; j++) acc[i][j] = ZERO4;
        auto loadA2 = [&](bf16x8* af, int k32) {
            int kk = (k32 << 5) + quad * 8;
            #pragma unroll
            for (int mt = 0; mt < 2; mt++)
                af[mt] = *(const bf16x8*)&hbf[(mt * 16 + l15) * GLDS + kk];
        };
        auto loadW2 = [&](bf16x8* wf, int k32) {
            const bf16s* p = w2base + ((size_t)k32 << 11);
            #pragma unroll
            for (int nt = 0; nt < 4; nt++)
                wf[nt] = *(const bf16x8*)(p + nt * 512);
        };
        loadA2(aA, 0); loadW2(wA, 0);
        for (int k32 = 0; k32 < 8; k32 += 2) {
            loadA2(aB, k32 + 1); loadW2(wB, k32 + 1);
            #pragma unroll
            for (int mt = 0; mt < 2; mt++)
                #pragma unroll
                for (int nt = 0; nt < 4; nt++)
                    acc[mt][nt] = MFMA16(aA[mt], wA[nt], acc[mt][nt]);
            if (k32 + 2 < 8) { loadA2(aA, k32 + 2); loadW2(wA, k32 + 2); }
            #pragma unroll
            for (int mt = 0; mt < 2; mt++)
                #pragma unroll
                for (int nt = 0; nt < 4; nt++)
                    acc[mt][nt] = MFMA16(aB[mt], wB[nt], acc[mt][nt]);
        }
        #pragma unroll
        for (int mt = 0; mt < 2; mt++)
            #pragma unroll
            for (int nt = 0; nt < 4; nt++)
                #pragma unroll
                for (int rr = 0; rr < 4; rr++) {
                    int row = mt * 16 + quad * 4 + rr;
                    int col = col0 + nt * 16 + l15;
                    float v = acc[mt][nt][rr] + bg2[col];
                    float g = 1.f / (1.f + __expf(-v));
                    e32[mt][nt][rr] += g * b2f(cxb[row * GLDS + col]);
                }
        if (r < 2) {
            #pragma unroll
            for (int mt = 0; mt < 2; mt++)
                #pragma unroll
                for (int nt = 0; nt < 4; nt++)
                    #pragma unroll
                    for (int rr = 0; rr < 4; rr++) {
                        int row = mt * 16 + quad * 4 + rr;
                        int col = col0 + nt * 16 + l15;
                        ebf[row * GLDS + col] = f2b(e32[mt][nt][rr]);
                    }
        }
    }

    // final: write updated e (bf16 only; the f32 copy is dead downstream)
    #pragma unroll
    for (int mt = 0; mt < 2; mt++)
        #pragma unroll
        for (int nt = 0; nt < 4; nt++)
            #pragma unroll
            for (int rr = 0; rr < 4; rr++) {
                int row = r0 + mt * 16 + quad * 4 + rr;
                if (row < M)
                    xb[(size_t)row * HIDC + col0 + nt * 16 + l15] = f2b(e32[mt][nt][rr]);
            }
}

// ---------------- flash v9: packed-K + 64 q-rows/wave + 4-way K-split ----------
__global__ __launch_bounds__(256) void flash8(const bf16s* __restrict__ qkv,
                                              const bf16s* __restrict__ vtb,
                                              const bf16s* __restrict__ ktb,
                                              bf16s* __restrict__ ctxall)
{
    __shared__ bf16s L[4][64 * 40];      // 20,480 B  P-tiles
    __shared__ float CMB[3][16][64];     // 12,288 B  combine (two passes: a0 then a1)
    __shared__ float CLS[3][4][64];      //  3,072 B  combine ls
    int bx = blockIdx.x;
    int sbg = bx >> 6, hb = bx & 63;
    int h = hb & 7, b = hb >> 3;
    int p = 0;
    while (sbg >= FP_SB0[p + 1]) p++;
    int wave = threadIdx.x >> 6, lane = threadIdx.x & 63;
    int l15 = lane & 15, quad = lane >> 4;
    int Sq = FP_SQ[p], Sk = FP_SK[p];
    bool ksp = (p < 3);
    int qrow0 = ksp ? (sbg - FP_SB0[p]) * 64
                    : ((sbg - FP_SB0[p]) * 4 + wave) * 64;
    if (qrow0 >= Sq) return;            // block-uniform when ksp (never taken there)
    int k0 = ksp ? wave * 784 : 0;
    int klim = ksp ? 784 : Sk;
    int qoff = FP_QOFF[p], koff = FP_KOFF[p];
    int voff = FP_VOFF[p], skp = FP_SKP[p];
    bf16s* ctxr = ctxall + (size_t)FP_R[p] * TTOK * HIDC;

    const bf16s* qrow = qkv + (size_t)(qoff + b * Sq) * QKVS + h * HDIM + quad * 8;
    bf16x8 qf[4];
    #pragma unroll
    for (int qi = 0; qi < 4; qi++)
        qf[qi] = *(const bf16x8*)(qrow + (size_t)min(qrow0 + qi * 16 + l15, Sq - 1) * QKVS);

    // packed K: wave's 16-row frag load = one contiguous 2KB block
    const bf16s* kp0 = ktb + ((size_t)h * TTOK + koff + b * Sk + k0 + l15) * 32 + quad * 8;
    const bf16s* kp16 = kp0 + 512;
    const bf16s* vp0 = vtb + (size_t)(h * HDIM + l15) * VTP + voff + b * skp + quad * 8;
    const bf16s* vp16 = vp0 + (size_t)16 * VTP;
    bf16s* Lw = L[wave];

    f32x4 a0[4], a1[4];   // a{dimhalf}[qi]
    float ls[4];
    #pragma unroll
    for (int qi = 0; qi < 4; qi++) { a0[qi] = ZERO4; a1[qi] = ZERO4; ls[qi] = 0.f; }
    int niter = (klim + 31) >> 5;

    bf16x8 kA0, kA1, vA0, vA1, kB0, kB1, vB0, vB1;

    auto loadKV = [&](bf16x8& kf0, bf16x8& kf1, bf16x8& vf0, bf16x8& vf1, int t) {
        size_t kb = (size_t)t << 10;
        kf0 = *(const bf16x8*)(kp0 + kb);
        kf1 = *(const bf16x8*)(kp16 + kb);
        vf0 = *(const bf16x8*)(vp0 + k0 + (t << 5));
        vf1 = *(const bf16x8*)(vp16 + k0 + (t << 5));
    };
    auto compute = [&](bf16x8 kf0, bf16x8 kf1, bf16x8 vf0, bf16x8 vf1, int t) {
        int kt = t << 5;
        f32x4 s0[4], s1[4];
        #pragma unroll
        for (int qi = 0; qi < 4; qi++) {
            s0[qi] = MFMA16(kf0, qf[qi], ZERO4);
            s1[qi] = MFMA16(kf1, qf[qi], ZERO4);
        }
        float p0[4][4], p1[4][4];
        #pragma unroll
        for (int qi = 0; qi < 4; qi++)
            #pragma unroll
            for (int r = 0; r < 4; r++) {
                p0[qi][r] = ex2(s0[qi][r]);
                p1[qi][r] = ex2(s1[qi][r]);
            }
        if (kt + 32 > klim) {  // tail: zero p for k >= klim (wave-uniform branch)
            int lim0 = klim - kt - quad * 4, lim1 = lim0 - 16;
            #pragma unroll
            for (int qi = 0; qi < 4; qi++)
                #pragma unroll
                for (int r = 0; r < 4; r++) {
                    if (r >= lim0) p0[qi][r] = 0.f;
                    if (r >= lim1) p1[qi][r] = 0.f;
                }
        }
        #pragma unroll
        for (int qi = 0; qi < 4; qi++) {
            #pragma unroll
            for (int r = 0; r < 4; r++) ls[qi] += p0[qi][r] + p1[qi][r];
            *(uint2*)&Lw[(qi * 16 + l15) * 40 + quad * 4] =
                make_uint2(cvtpk(p0[qi][0], p0[qi][1]), cvtpk(p0[qi][2], p0[qi][3]));
            *(uint2*)&Lw[(qi * 16 + l15) * 40 + 16 + quad * 4] =
                make_uint2(cvtpk(p1[qi][0], p1[qi][1]), cvtpk(p1[qi][2], p1[qi][3]));
        }
        #pragma unroll
        for (int qi = 0; qi < 4; qi++) {
            bf16x8 pb = *(const bf16x8*)&Lw[(qi * 16 + l15) * 40 + quad * 8];
            a0[qi] = MFMA16(vf0, pb, a0[qi]);
            a1[qi] = MFMA16(vf1, pb, a1[qi]);
        }
    };

    loadKV(kA0, kA1, vA0, vA1, 0);
    for (int t = 0; t < niter; t += 2) {
        if (t + 1 < niter) loadKV(kB0, kB1, vB0, vB1, t + 1);
        compute(kA0, kA1, vA0, vA1, t);
        if (t + 2 < niter) loadKV(kA0, kA1, vA0, vA1, t + 2);
        if (t + 1 < niter) compute(kB0, kB1, vB0, vB1, t + 1);
    }

    if (ksp) {
        // two-pass LDS combine across the 4 k-chunk waves (keeps LDS <= 36 KB)
        if (wave > 0) {
            #pragma unroll
            for (int qi = 0; qi < 4; qi++) {
                #pragma unroll
                for (int r = 0; r < 4; r++) CMB[wave - 1][qi * 4 + r][lane] = a0[qi][r];
                CLS[wave - 1][qi][lane] = ls[qi];
            }
        }
        __syncthreads();
        if (wave == 0) {
            #pragma unroll
            for (int w = 0; w < 3; w++)
                #pragma unroll
                for (int qi = 0; qi < 4; qi++) {
                    #pragma unroll
                    for (int r = 0; r < 4; r++) a0[qi][r] += CMB[w][qi * 4 + r][lane];
                    ls[qi] += CLS[w][qi][lane];
                }
        }
        __syncthreads();
        if (wave > 0) {
            #pragma unroll
            for (int qi = 0; qi < 4; qi++)
                #pragma unroll
                for (int r = 0; r < 4; r++) CMB[wave - 1][qi * 4 + r][lane] = a1[qi][r];
        }
        __syncthreads();
        if (wave > 0) return;
        #pragma unroll
        for (int w = 0; w < 3; w++)
            #pragma unroll
            for (int qi = 0; qi < 4; qi++)
                #pragma unroll
                for (int r = 0; r < 4; r++) a1[qi][r] += CMB[w][qi * 4 + r][lane];
    }

    #pragma unroll
    for (int qi = 0; qi < 4; qi++) {
        float l = ls[qi];
        l += __shfl_xor(l, 16); l += __shfl_xor(l, 32);
        float inv = 1.f / l;
        if (qrow0 + qi * 16 + l15 < Sq) {
            size_t o = (size_t)(qoff + b * Sq + qrow0 + qi * 16 + l15) * HIDC + h * HDIM;
            *(uint2*)(ctxr + o + quad * 4) =
                make_uint2(cvtpk(a0[qi][0] * inv, a0[qi][1] * inv),
                           cvtpk(a0[qi][2] * inv, a0[qi][3] * inv));
            *(uint2*)(ctxr + o + 16 + quad * 4) =
                make_uint2(cvtpk(a1[qi][0] * inv, a1[qi][1] * inv),
                           cvtpk(a1[qi][2] * inv, a1[qi][3] * inv));
        }
    }
}

// ---------------- CECM: pooled mean partials over all scales ----------------
__global__ __launch_bounds__(256) void pool2(const bf16s* __restrict__ xb,
                                             float* __restrict__ partial) {
    int chunk = blockIdx.x, b = blockIdx.y, i = blockIdx.z;
    int c = threadIdx.x;
    int S = DC_S[i];
    int len = (S + 31) / 32;
    int s0 = chunk * len, s1 = min(S, s0 + len);
    float acc = 0.f;
    const bf16s* base = xb + (size_t)(DC_BOFF[i] + b * S) * HIDC + c;
    for (int s = s0; s < s1; s++) acc += b2f(base[(size_t)s * HIDC]);
    partial[(size_t)((i * NB + b) * 32 + chunk) * HIDC + c] = acc;
}

// ---------------- CECM: kernel generator MLP (all scales) ----------------
__global__ __launch_bounds__(256) void kgen2(
    const float* __restrict__ partial,
    const float* __restrict__ Wcp, const float* __restrict__ bcp,
    const float* __restrict__ Wkg1, const float* __restrict__ bkg1,
    const float* __restrict__ Wkg2, const float* __restrict__ bkg2,
    float* __restrict__ kern)
{
    __shared__ float pl[256], cv[256], h1[512];
    int b = blockIdx.x, i = blockIdx.y, t = threadIdx.x;
    float invS = 1.f / (float)DC_S[i];
    const float* pb = partial + (size_t)((i * NB + b) * 32) * HIDC;
    float s = 0.f;
    for (int jc = 0; jc < 32; jc++) s += pb[(size_t)jc * HIDC + t];
    pl[t] = s * invS;
    __syncthreads();
    float a = bcp[t];
    for (int k = 0; k < 256; k++) a += Wcp[t * 256 + k] * pl[k];
    cv[t] = fmaxf(a, 0.f);
    __syncthreads();
    for (int r = t; r < 512; r += 256) {
        float a2 = bkg1[r];
        for (int k = 0; k < 256; k++) a2 += Wkg1[r * 256 + k] * cv[k];
        h1[r] = fmaxf(a2, 0.f);
    }
    __syncthreads();
    if (t < 72) {
        float a3 = bkg2[t];
        for (int k = 0; k < 512; k++) a3 += Wkg2[t * 512 + k] * h1[k];
        kern[(i * NB + b) * 72 + t] = a3;
    }
}

// ---------------- CECM: fused dynamic depthwise 3x3 over all scales ----------------
__global__ __launch_bounds__(256) void dwconv2(const bf16s* __restrict__ xtb,
                                               const float* __restrict__ kern,
                                               bf16s* __restrict__ y) {
    int tok = blockIdx.x;
    int i = (tok >= DC_BOFF[1]) + (tok >= DC_BOFF[2]) + (tok >= DC_BOFF[3]);
    int S = DC_S[i], W = DC_HW[i];
    int local = tok - DC_BOFF[i];
    int b = local / S, s = local - b * S;
    int hh = s / W, ww = s - hh * W;
    int c = threadIdx.x;
    const float* kb = kern + (i * NB + b) * 72 + (c >> 5) * 9;
    const bf16s* xbase = xtb + (size_t)(DC_BOFF[i] + b * S) * HIDC + c;
    float acc = 0.f;
    #pragma unroll
    for (int ky = 0; ky < 3; ky++) {
        int hy = hh + ky - 1;
        if (hy < 0 || hy >= W) continue;
        #pragma unroll
        for (int kx = 0; kx < 3; kx++) {
            int wx = ww + kx - 1;
            if (wx < 0 || wx >= W) continue;
            acc += kb[ky * 3 + kx] * b2f(xbase[(size_t)(hy * W + wx) * HIDC]);
        }
    }
    y[(size_t)tok * HIDC + c] = f2b(acc);
}

// ---------------- BN stats v2: 512 blocks, float4 loads, LDS row-group reduce ----------
__global__ __launch_bounds__(256) void bn1(const float* __restrict__ yo,
                                           float* __restrict__ bnp) {
    __shared__ float red[4][64][8];
    int chunk = blockIdx.x, i = blockIdx.y, t = threadIdx.x;
    int rg = t >> 6, cq = (t & 63) * 4;
    int Nrows = NB * DC_S[i];
    const float* base = yo + (size_t)DC_BOFF[i] * HIDC + cq;
    f32x4 s = ZERO4, ss = ZERO4;
    for (int r = chunk * 4 + rg; r < Nrows; r += BN1_CH * 4) {
        f32x4 v = *(const f32x4*)(base + (size_t)r * HIDC);
        s += v; ss += v * v;
    }
    #pragma unroll
    for (int j = 0; j < 4; j++) { red[rg][t & 63][j] = s[j]; red[rg][t & 63][4 + j] = ss[j]; }
    __syncthreads();
    if (t < 64) {
        #pragma unroll
        for (int j = 0; j < 4; j++) {
            float a = red[0][t][j] + red[1][t][j] + red[2][t][j] + red[3][t][j];
            float b = red[0][t][4 + j] + red[1][t][4 + j] + red[2][t][4 + j] + red[3][t][4 + j];
            bnp[(size_t)(i * BN1_CH + chunk) * 512 + t * 4 + j] = a;
            bnp[(size_t)(i * BN1_CH + chunk) * 512 + 256 + t * 4 + j] = b;
        }
    }
}
__global__ __launch_bounds__(256) void bn2(const float* __restrict__ bnp,
                                           float* __restrict__ stat) {
    int i = blockIdx.x, c = threadIdx.x;
    float s = 0.f, ss = 0.f;
    for (int ch = 0; ch < BN1_CH; ch++) {
        s += bnp[(size_t)(i * BN1_CH + ch) * 512 + c];
        ss += bnp[(size_t)(i * BN1_CH + ch) * 512 + 256 + c];
    }
    float inv = 1.f / (float)(NB * DC_S[i]);
    float mu = s * inv;
    float var = fmaxf(ss * inv - mu * mu, 0.f);
    stat[i * 512 + c] = mu;
    stat[i * 512 + 256 + c] = rsqrtf(var + 1e-5f);
}

// ---------------- fused final output (tiled transpose), all scales ----------------
__global__ __launch_bounds__(256) void final2(const bf16s* __restrict__ xtb,
                                              const float* __restrict__ yo,
                                              const float* __restrict__ stat,
                                              const float* __restrict__ gamma,
                                              const float* __restrict__ beta,
                                              float* __restrict__ out) {
    __shared__ float tile[64][65];
    int bx = blockIdx.x;
    int i = (bx >= DC_FOS[1]) + (bx >= DC_FOS[2]) + (bx >= DC_FOS[3]);
    int S = DC_S[i];
    int s0 = (bx - DC_FOS[i]) * 64;
    int cstrip = blockIdx.y, b = blockIdx.z;
    int g = threadIdx.x >> 6, sl = threadIdx.x & 63;
    {
        int c = cstrip * 64 + sl;
        float mu = stat[i * 512 + c], rstd = stat[i * 512 + 256 + c];
        float ga = gamma[c], be = beta[c];
        size_t rbase = (size_t)(DC_BOFF[i] + b * S) * HIDC + c;
        #pragma unroll
        for (int u = 0; u < 16; u++) {
            int s = s0 + g * 16 + u;
            if (s < S) {
                size_t r = rbase + (size_t)s * HIDC;
                tile[g * 16 + u][sl] = b2f(xtb[r]) + (yo[r] - mu) * rstd * ga + be;
            }
        }
    }
    __syncthreads();
    {
        int s = s0 + sl;
        if (s < S) {
            #pragma unroll
            for (int cs = 0; cs < 16; cs++) {
                int cl = g * 16 + cs;
                out[((size_t)(b * HIDC + cstrip * 64 + cl)) * STOT + DC_GOFF[i] + s] = tile[sl][cl];
            }
        }
    }
}

// ---------------- host helpers ----------------
static inline void gemm_launch(hipStream_t st, const bf16s* A, const bf16s* A2,
                               const bf16s* W, const float* bias,
                               float* Cf, bf16s* Cb, const bf16s* Gaux,
                               int M, int N, int K, int K1, int epi) {
    dim3 grid(N / 128, (M + 63) / 64), blk(256);
    switch (epi) {
        case 0: gemm3<0><<<grid, blk, 0, st>>>(A, A2, W, bias, Cf, Cb, Gaux, M, N, K, K1); break;
        case 1: gemm3<1><<<grid, blk, 0, st>>>(A, A2, W, bias, Cf, Cb, Gaux, M, N, K, K1); break;
        case 5: gemm3<5><<<grid, blk, 0, st>>>(A, A2, W, bias, Cf, Cb, Gaux, M, N, K, K1); break;
        default: gemm3<4><<<grid, blk, 0, st>>>(A, A2, W, bias, Cf, Cb, Gaux, M, N, K, K1); break;
    }
}

extern "C" void kernel_launch(void* const* d_in, const int* in_sizes, int n_in,
                              void* d_out, int out_size, void* d_ws, size_t ws_size,
                              hipStream_t stream) {
    typedef const float* fp;
    fp f[4]  = {(fp)d_in[0], (fp)d_in[3], (fp)d_in[6], (fp)d_in[9]};
    fp Wp[4] = {(fp)d_in[1], (fp)d_in[4], (fp)d_in[7], (fp)d_in[10]};
    fp bp[4] = {(fp)d_in[2], (fp)d_in[5], (fp)d_in[8], (fp)d_in[11]};
    fp Wq = (fp)d_in[12], Wk = (fp)d_in[13], Wv = (fp)d_in[14], Wo = (fp)d_in[15];
    fp Wg1 = (fp)d_in[16], Wg2 = (fp)d_in[17], Wcp = (fp)d_in[18];
    fp Wkg1 = (fp)d_in[19], Wkg2 = (fp)d_in[20], Wit = (fp)d_in[21], Wot = (fp)d_in[22];
    fp bq = (fp)d_in[23], bk = (fp)d_in[24], bv = (fp)d_in[25], bo = (fp)d_in[26];
    fp bg1 = (fp)d_in[27], bg2 = (fp)d_in[28], bcp = (fp)d_in[29];
    fp bkg1 = (fp)d_in[30], bkg2 = (fp)d_in[31], bit = (fp)d_in[32], bot = (fp)d_in[33];
    fp gamma = (fp)d_in[34], beta = (fp)d_in[35];
    float* out = (float*)d_out;

    const size_t NT = (size_t)TTOK * HIDC;   // 8,529,920

    // ---- workspace carve ----
    float* x     = (float*)d_ws;               // e f32; phase 4: yo aliases x
    bf16s* xb    = (bf16s*)(x + NT);           // e bf16 mirror
    bf16s* qkvb  = xb + NT;                    // [TTOK, 768] (Q section live; K/V go to ktb/vtb)
    bf16s* vtb   = qkvb + (size_t)TTOK * QKVS; // [256][VTP] (zero-filled)
    bf16s* ctxall= vtb + (size_t)HIDC * VTP;   // 3 x [TTOK,256] flash ctx
    bf16s* ctxob = ctxall + 3 * NT;            // repurposed: ktb (packed K)
    float* partial = (float*)(ctxob + 3 * NT);
    float* kern    = partial + 4 * NB * 32 * HIDC;
    float* bnp     = kern + 4 * NB * 72;
    float* bnstat  = bnp + 4 * 32 * 512;
    float* bqkv    = bnstat + 4 * 512;         // 768
    bf16s* wseg    = (bf16s*)(bqkv + 768);
    // aliases
    bf16s* atmp = ctxall;                      // phase-1 scratch
    bf16s* hb   = ctxall;                      // dwconv out (phase 4; ctxall dead then)
    bf16s* xtb  = ctxall + NT;                 // Wit out (phase 4)
    float* yo   = x;                           // phase-4 Wot out (e f32 dead)
    float* bnp2 = partial;                     // bn1 partials reuse `partial`
    bf16s* ktb  = ctxob;                       // packed K [8][TTOK][32]
    bf16s* ctxob2 = qkvb;                      // Wo out: qkvb region (3NT exact), dead after flash

    // weight pointers in wseg (all bf16 weights stored SWIZZLED)
    bf16s* wpb[4]; size_t wo_ = 0;
    for (int i = 0; i < 4; i++) { wpb[i] = wseg + wo_; wo_ += (size_t)HIDC * D_IN[i]; }
    bf16s* wqkvb = wseg + wo_; wo_ += (size_t)QKVS * 256;
    bf16s* wob  = wseg + wo_; wo_ += 65536;
    bf16s* wg1b = wseg + wo_; wo_ += 131072;
    bf16s* wg2b = wseg + wo_; wo_ += 65536;
    bf16s* witb = wseg + wo_; wo_ += 65536;
    bf16s* wotb = wseg + wo_; wo_ += 65536;

    // ---- fused weight conversion + swizzle (Wq/bq pre-scaled by 1/sqrt(32)*log2e) ----
    {
        CvtArgs ca;
        const float* srcs[15] = {Wp[0], Wp[1], Wp[2], Wp[3], Wq, Wk, Wv, Wo, Wg1, Wg2,
                                 Wit, Wot, bq, bk, bv};
        void* dsts[15] = {wpb[0], wpb[1], wpb[2], wpb[3], wqkvb, wqkvb + 65536,
                          wqkvb + 131072, wob, wg1b, wg2b, witb, wotb,
                          bqkv, bqkv + 256, bqkv + 512};
        int ns[15] = {16384, 32768, 65536, 131072, 65536, 65536, 65536, 65536, 131072,
                      65536, 65536, 65536, 256, 256, 256};
        int modes[15] = {0, 0, 0, 0, 1, 0, 0, 0, 0, 0, 0, 0, 3, 2, 2};
        int Ks[15] = {64, 128, 256, 512, 256, 256, 256, 256, 512, 256, 256, 256, 0, 0, 0};
        int total = 0;
        for (int k = 0; k < 15; k++) { ca.src[k] = srcs[k]; ca.dst[k] = dsts[k];
                                       ca.n[k] = ns[k]; ca.mode[k] = modes[k];
                                       ca.K[k] = Ks[k]; total += ns[k]; }
        cvt_all<<<dim3((total + 255) / 256), dim3(256), 0, stream>>>(ca, total);
    }
    // zero vtb so pad regions / unguarded tail reads are finite
    hipMemsetAsync(vtb, 0, (size_t)HIDC * VTP * sizeof(bf16s), stream);

    // ---- phase 1: per-scale 1x1 projection -> x (f32) + xb (bf16) ----
    for (int i = 0; i < 4; i++) {
        int S = S_SZ[i], D = D_IN[i], M = NB * S;
        transpose_f2<<<dim3((S + 31) / 32, D / 32, NB), dim3(256), 0, stream>>>(f[i], atmp, D, S);
        gemm_launch(stream, atmp, nullptr, wpb[i], bp[i],
                    x + (size_t)BOFF[i] * HIDC, xb + (size_t)BOFF[i] * HIDC, nullptr,
                    M, HIDC, D, D, 1);
    }

    // ---- phase 2: merged QKV GEMM with scatter epilogue (Q->qkvb, K->ktb, V->vtb) ----
    gemm_launch(stream, xb, nullptr, wqkvb, bqkv, (float*)ktb, qkvb, vtb,
                TTOK, QKVS, 256, 256, 5);

    // ---- phase 3: flash, batched Wo (out -> dead qkvb region), fused gate chain ----
    flash8<<<dim3(69 * 64), dim3(256), 0, stream>>>(qkvb, vtb, ktb, ctxall);
    gemm_launch(stream, ctxall, nullptr, wob, bo, nullptr, ctxob2, nullptr, 3 * TTOK, HIDC, 256, 256, 0);
    gatefuse<<<dim3((TTOK + 31) / 32), dim3(256), 0, stream>>>(
        ctxob2, xb, x, wg1b, bg1, wg2b, bg2, TTOK);

    // ---- phase 4: CECM fused across scales ----
    pool2<<<dim3(32, NB, 4), dim3(256), 0, stream>>>(xb, partial);
    kgen2<<<dim3(NB, 4), dim3(256), 0, stream>>>(partial, Wcp, bcp, Wkg1, bkg1, Wkg2, bkg2, kern);
    gemm_launch(stream, xb, nullptr, witb, bit, nullptr, xtb, nullptr, TTOK, HIDC, 256, 256, 0);
    dwconv2<<<dim3(TTOK), dim3(256), 0, stream>>>(xtb, kern, hb);
    gemm_launch(stream, hb, nullptr, wotb, bot, yo, nullptr, nullptr, TTOK, HIDC, 256, 256, 4);
    bn1<<<dim3(BN1_CH, 4), dim3(256), 0, stream>>>(yo, bnp2);
    bn2<<<dim3(4), dim3(256), 0, stream>>>(bnp2, bnstat);
    final2<<<dim3(67, 4, NB), dim3(256), 0, stream>>>(xtb, yo, bnstat, gamma, beta, out);
}